// Round 6
// baseline (574.536 us; speedup 1.0000x reference)
//
#include <hip/hip_runtime.h>
#include <math.h>

#define N 8192
#define FIN 512
#define FOUT 256
#define NEGV (-9e15f)
#define NCAND 16
#define HMAX 64
#define USTR 516   // LDS row stride (516%32=4 -> <=2-way bank aliasing = free)

typedef long long ll;

// ---------------- kernel 0: mui softmax + derived params + zero ctrl ----------------
__global__ void params_kernel(const float* __restrict__ Mui, float* __restrict__ params,
                              float* __restrict__ wfrob2, unsigned* __restrict__ hnmaxbits) {
    if (threadIdx.x == 0) {
        float m = Mui[0];
        for (int i = 1; i < 6; ++i) m = fmaxf(m, Mui[i]);
        float e[6], s = 0.f;
        for (int i = 0; i < 6; ++i) { e[i] = expf(Mui[i] - m); s += e[i]; }
        float mui[6];
        for (int i = 0; i < 6; ++i) mui[i] = e[i] / s;
        params[0] = mui[0] + mui[1] + mui[2] + mui[3];                    // a (G coefficient)
        params[1] = 0.5f * (mui[0] + mui[1]) + 1.0f * (mui[2] + mui[3]); // additive const
        params[2] = 256.0f * mui[4];                                      // D*mui4
        params[3] = 256.0f * mui[5];                                      // D*mui5
        *wfrob2 = 0.f;
        *hnmaxbits = 0u;
    }
}

// ---------------- kernel 1: ||W||_F^2 + extract W[:,1] ----------------
__global__ __launch_bounds__(256) void wfrob_kernel(const float* __restrict__ W,
                                                    float* __restrict__ wfrob2,
                                                    float* __restrict__ wcol1) {
    int idx4 = (blockIdx.x * 256 + threadIdx.x) * 4;   // FIN*FOUT = 131072 elems, 128 blocks
    float4 v = *(const float4*)&W[idx4];
    if ((idx4 & 255) == 0) wcol1[idx4 >> 8] = v.y;     // column 1 of row idx4>>8
    float s = v.x * v.x + v.y * v.y + v.z * v.z + v.w * v.w;
#pragma unroll
    for (int off = 1; off < 64; off <<= 1) s += __shfl_xor(s, off, 64);
    if ((threadIdx.x & 63) == 0) atomicAdd(wfrob2, s);
}

// ---------------- kernel 2: per-row t1 (GEMV vs W[:,1]), ||h_i||, factors ----------------
__global__ __launch_bounds__(256) void rowstats_kernel(
    const float* __restrict__ h, const float* __restrict__ params,
    const float* __restrict__ wcol1,
    float* __restrict__ t1a, float* __restrict__ x1, float* __restrict__ x2,
    float* __restrict__ w1, float* __restrict__ w2,
    float* __restrict__ hn, unsigned* __restrict__ hnmaxbits) {
    __shared__ float wc[FIN];
    const int t = threadIdx.x;
    ((float2*)wc)[t] = ((const float2*)wcol1)[t];
    __syncthreads();
    const int w = t >> 6, lane = t & 63;
    const int i = blockIdx.x * 4 + w;
    const float4* hp = (const float4*)&h[(ll)i * FIN + lane * 8];
    float4 a = hp[0], b = hp[1];
    const float4* wv = (const float4*)&wc[lane * 8];
    float4 c0 = wv[0], c1 = wv[1];
    float s = a.x * c0.x + a.y * c0.y + a.z * c0.z + a.w * c0.w
            + b.x * c1.x + b.y * c1.y + b.z * c1.z + b.w * c1.w;
    float n = a.x * a.x + a.y * a.y + a.z * a.z + a.w * a.w
            + b.x * b.x + b.y * b.y + b.z * b.z + b.w * b.w;
#pragma unroll
    for (int off = 1; off < 64; off <<= 1) {
        s += __shfl_xor(s, off, 64);
        n += __shfl_xor(n, off, 64);
    }
    if (lane == 0) {
        float t1 = s * s;
        t1a[i] = t1;
        x1[i] = expf(0.5f * t1);
        x2[i] = expf(t1);
        w1[i] = params[2] * expf(-0.5f * t1);
        w2[i] = params[3] * expf(-t1);
        float nr = sqrtf(n);
        hn[i] = nr;
        atomicMax(hnmaxbits, __float_as_uint(nr));   // nr > 0 -> bit-monotone
    }
}

// ---------------- kernel 3a: per-slice top-16 ----------------
__global__ __launch_bounds__(64) void topk1_kernel(const float* __restrict__ t1a,
                                                   float* __restrict__ o1v,
                                                   int* __restrict__ o1i) {
    const int l = threadIdx.x;
    const int base = blockIdx.x * 128;
    float v0 = t1a[base + l], v1 = t1a[base + 64 + l];
    int i0 = base + l, i1 = base + 64 + l;
    for (int r = 0; r < NCAND; ++r) {
        float mv; int mi;
        if (v0 >= v1) { mv = v0; mi = i0; } else { mv = v1; mi = i1; }
#pragma unroll
        for (int off = 1; off < 64; off <<= 1) {
            float ov = __shfl_xor(mv, off, 64);
            int   oi = __shfl_xor(mi, off, 64);
            if (ov > mv || (ov == mv && oi < mi)) { mv = ov; mi = oi; }
        }
        if (mi == i0) v0 = -2.f;
        if (mi == i1) v1 = -2.f;
        if (l == r) { o1v[blockIdx.x * NCAND + r] = mv; o1i[blockIdx.x * NCAND + r] = mi; }
    }
}

// ---------------- kernel 3b: global top-16 (1 block) ----------------
__global__ __launch_bounds__(1024) void topk2_kernel(
    const float* __restrict__ o1v, const int* __restrict__ o1i,
    const float* __restrict__ t1a, const float* __restrict__ x1, const float* __restrict__ x2,
    int* __restrict__ cidx, float* __restrict__ ct1, float* __restrict__ cx1,
    float* __restrict__ cx2, float* __restrict__ ubx, int* __restrict__ hardcnt) {
    __shared__ float lv[16];
    __shared__ int li[16];
    __shared__ float bvs;
    __shared__ int bis;
    const int t = threadIdx.x;
    float v = o1v[t];
    int idx = o1i[t];
    for (int r = 0; r < NCAND; ++r) {
        float mv = v; int mi = idx;
#pragma unroll
        for (int off = 1; off < 64; off <<= 1) {
            float ov = __shfl_xor(mv, off, 64);
            int   oi = __shfl_xor(mi, off, 64);
            if (ov > mv || (ov == mv && oi < mi)) { mv = ov; mi = oi; }
        }
        if ((t & 63) == 0) { lv[t >> 6] = mv; li[t >> 6] = mi; }
        __syncthreads();
        if (t < 64) {
            float m2 = (t < 16) ? lv[t] : -3.f;
            int   i2 = (t < 16) ? li[t] : -1;
#pragma unroll
            for (int off = 1; off < 16; off <<= 1) {
                float ov = __shfl_xor(m2, off, 64);
                int   oi = __shfl_xor(i2, off, 64);
                if (ov > m2 || (ov == m2 && oi < i2)) { m2 = ov; i2 = oi; }
            }
            if (t == 0) { bvs = m2; bis = i2; }
        }
        __syncthreads();
        if (idx == bis) v = -2.f;
        if (t == r) cidx[r] = bis;
    }
    __syncthreads();
    if (t < NCAND) {
        int j = cidx[t];
        ct1[t] = t1a[j];
        cx1[t] = x1[j];
        cx2[t] = x2[j];
    }
    if (t == 0) {
        int j = cidx[NCAND - 1];
        ubx[0] = x1[j];
        ubx[1] = x2[j];
        *hardcnt = 0;
    }
}

// ---------------- kernel 4: Wh rows of the 16 candidates -> ELU ----------------
__global__ __launch_bounds__(256) void candwh_kernel(const float* __restrict__ h,
                                                     const float* __restrict__ W,
                                                     const int* __restrict__ cidx,
                                                     float* __restrict__ celu) {
    __shared__ float hl[FIN];
    const int b = blockIdx.x, t = threadIdx.x;
    const int row = cidx[b];
    ((float2*)hl)[t] = ((const float2*)&h[(ll)row * FIN])[t];
    __syncthreads();
    float acc = 0.f;
#pragma unroll 8
    for (int k = 0; k < FIN; ++k) acc = fmaf(hl[k], W[k * FOUT + t], acc);
    celu[b * FOUT + t] = acc > 0.f ? acc : expm1f(acc);
}

// ---------------- kernel 4b: init hard accumulators + zero uarr ----------------
__global__ __launch_bounds__(256) void hardinit_kernel(float* __restrict__ uarr,
                                                       float* __restrict__ rowsum,
                                                       unsigned* __restrict__ rowmaxenc) {
    int b = blockIdx.x, t = threadIdx.x;
    uarr[b * FIN + t] = 0.f;
    uarr[b * FIN + t + 256] = 0.f;
    if (t == 0) { rowsum[b] = 0.f; rowmaxenc[b] = 0u; }
}

// ---------------- kernel 5: classify rows; write easy rows (one wave per row) ----------------
__global__ __launch_bounds__(256) void classify_kernel(
    const float* __restrict__ params, const int* __restrict__ adj,
    const int* __restrict__ cidx, const float* __restrict__ ct1,
    const float* __restrict__ cx1, const float* __restrict__ cx2,
    const float* __restrict__ ubx, const float* __restrict__ w1, const float* __restrict__ w2,
    const float* __restrict__ hn, const float* __restrict__ wfrob2,
    const unsigned* __restrict__ hnmaxbits, const float* __restrict__ celu,
    int* __restrict__ hardcnt, int* __restrict__ hardlist, float* __restrict__ out) {
    const int i = (blockIdx.x << 2) + (threadIdx.x >> 6);   // one 64-lane wave per row
    const int lane = threadIdx.x & 63;
    const bool valid = lane < NCAND;

    int   cj  = valid ? cidx[lane] : 0;
    float cT  = valid ? ct1[lane] : -1.f;
    float cX1 = valid ? cx1[lane] : 0.f;
    float cX2 = valid ? cx2[lane] : 0.f;
    int ad = valid ? adj[(ll)i * N + cj] : 0;
    unsigned long long m = __ballot(ad > 0);

    float w1i = w1[i], w2i = w2[i];
    bool hard = false;
    int f = -1;
    if (m == 0ull) {
        hard = true;   // no adjacent candidate -> exact fallback
    } else {
        f = __ffsll(m) - 1;
        float t1f = __shfl(cT, f, 64);
        float x1f = __shfl(cX1, f, 64);
        float x2f = __shfl(cX2, f, 64);
        float lastT = __shfl(cT, NCAND - 1, 64);
        unsigned long long tm = __ballot(ad > 0 && (cT == t1f));
        if (__popcll(tm) > 1 || t1f == lastT) hard = true;
        float Lx1 = w1i * x1f + w2i * x2f;
        unsigned long long m2 = m & ~(1ull << f);
        float Lx2 = -INFINITY;
        if (m2 != 0ull) {
            int s2 = __ffsll(m2) - 1;
            Lx2 = w1i * __shfl(cX1, s2, 64) + w2i * __shfl(cX2, s2, 64);
        }
        float ub  = w1i * ubx[0] + w2i * ubx[1];
        float alt = fmaxf(Lx2, ub);
        float wf  = sqrtf(*wfrob2);
        float hmx = __uint_as_float(*hnmaxbits);
        float margin = 2.04f * params[0] * (hn[i] * wf) * (hmx * wf)
                     + 100.0f + 1e-5f * fabsf(Lx1);
        if (!(Lx1 - alt > margin)) hard = true;    // NaN-safe: NaN -> hard
    }
    if (hard) {
        if (lane == 0) { int p = atomicAdd(hardcnt, 1); hardlist[p] = i; }
        return;
    }
    float4 v = ((const float4*)&celu[(ll)f * FOUT])[lane];
    ((float4*)&out[(ll)i * FOUT])[lane] = v;
}

// ---------------- kernel 6a: hard rows — u_s = W (W^T h_i) ----------------
__global__ __launch_bounds__(256) void hardprep_kernel(
    const float* __restrict__ h, const float* __restrict__ W,
    const int* __restrict__ hardcnt, const int* __restrict__ hardlist,
    float* __restrict__ uarr) {
    const int hh = blockIdx.x;
    const int nh = min(*hardcnt, HMAX);
    if (hh >= nh) return;
    const int i = hardlist[hh];
    __shared__ float hl[FIN];
    __shared__ float vl[FOUT];
    const int t = threadIdx.x;
    ((float2*)hl)[t] = ((const float2*)&h[(ll)i * FIN])[t];
    __syncthreads();
    float a = 0.f;
#pragma unroll 8
    for (int k = 0; k < FIN; ++k) a = fmaf(hl[k], W[k * FOUT + t], a);
    vl[t] = a;
    __syncthreads();
    float u0 = 0.f, u1 = 0.f;
#pragma unroll 8
    for (int c = 0; c < FOUT; ++c) {
        float vc = vl[c];
        u0 = fmaf(W[t * FOUT + c], vc, u0);
        u1 = fmaf(W[(t + 256) * FOUT + c], vc, u1);
    }
    uarr[hh * FIN + t] = u0;
    uarr[hh * FIN + t + 256] = u1;
}

// ---------------- kernel 6b: batched hard logits S = h.U, masked, + row max ----------------
// grid: 1024 = 256 j-chunks x 4 passes of 16 slots
__global__ __launch_bounds__(256) void hardS_kernel(
    const float* __restrict__ h, const float* __restrict__ params,
    const int* __restrict__ adj, const float* __restrict__ x1, const float* __restrict__ x2,
    const float* __restrict__ w1, const float* __restrict__ w2,
    const int* __restrict__ hardcnt, const int* __restrict__ hardlist,
    const float* __restrict__ uarr, float* __restrict__ ebuf,
    unsigned* __restrict__ rowmaxenc) {
    const int p = blockIdx.x >> 8;
    const int chunk = blockIdx.x & 255;
    const int nh = min(*hardcnt, HMAX);
    if (p * 16 >= nh) return;
    extern __shared__ float smem[];
    float* Us = smem;                 // 16*USTR
    float* Hs = Us + 16 * USTR;       // 16*USTR
    __shared__ float w1s[16], w2s[16];
    __shared__ int is_[16];
    __shared__ float wred[4][16];
    const int t = threadIdx.x;
#pragma unroll
    for (int r = 0; r < 32; ++r) {
        int idx = r * 256 + t;
        int uu = idx >> 9, k = idx & 511;
        Us[uu * USTR + k] = uarr[(p * 16 + uu) * FIN + k];
    }
    if (t < 16) {
        int slot = p * 16 + t;
        int ii = (slot < nh) ? hardlist[slot] : -1;
        is_[t] = ii;
        w1s[t] = (ii >= 0) ? w1[ii] : 0.f;
        w2s[t] = (ii >= 0) ? w2[ii] : 0.f;
    }
    __syncthreads();
    const float aC = params[0], cA = params[1];
    const int u = t & 15, jl = t >> 4;
    const int iu = is_[u];
    const float w1u = w1s[u], w2u = w2s[u];
    float mxl = -INFINITY;
    for (int jb = 0; jb < 2; ++jb) {
        __syncthreads();
#pragma unroll
        for (int r = 0; r < 32; ++r) {
            int idx = r * 256 + t;
            int jj = idx >> 9, k = idx & 511;
            Hs[jj * USTR + k] = h[(ll)(chunk * 32 + jb * 16 + jj) * FIN + k];
        }
        __syncthreads();
        const float4* up = (const float4*)&Us[u * USTR];
        const float4* hp = (const float4*)&Hs[jl * USTR];
        float s = 0.f;
#pragma unroll 8
        for (int k4 = 0; k4 < 128; ++k4) {
            float4 a = hp[k4], b = up[k4];
            s = fmaf(a.x, b.x, fmaf(a.y, b.y, fmaf(a.z, b.z, fmaf(a.w, b.w, s))));
        }
        int j = chunk * 32 + jb * 16 + jl;
        float ev = fmaf(aC, s, cA);
        ev = fmaf(w1u, x1[j], ev);
        ev = fmaf(w2u, x2[j], ev);
        int ad = (iu >= 0) ? adj[(ll)iu * N + j] : 0;
        ev = (ad > 0) ? ev : NEGV;
        if (iu >= 0) {
            ebuf[(ll)j * HMAX + p * 16 + u] = ev;
            mxl = fmaxf(mxl, ev);
        }
    }
    mxl = fmaxf(mxl, __shfl_xor(mxl, 16, 64));
    mxl = fmaxf(mxl, __shfl_xor(mxl, 32, 64));
    if ((t & 63) < 16) wred[t >> 6][u] = mxl;
    __syncthreads();
    if (t < 16 && is_[t] >= 0) {
        float m = fmaxf(fmaxf(wred[0][t], wred[1][t]), fmaxf(wred[2][t], wred[3][t]));
        unsigned ub = __float_as_uint(m);
        unsigned enc = (ub & 0x80000000u) ? ~ub : (ub | 0x80000000u);
        atomicMax(&rowmaxenc[p * 16 + t], enc);
    }
}

// ---------------- kernel 6c: batched exp/sum + per-chunk weighted-h partials ----------------
__global__ __launch_bounds__(256) void hardP_kernel(
    const float* __restrict__ h, const int* __restrict__ hardcnt,
    const float* __restrict__ ebuf, const unsigned* __restrict__ rowmaxenc,
    float* __restrict__ rowsum, float* __restrict__ gpart) {
    const int p = blockIdx.x >> 8;
    const int chunk = blockIdx.x & 255;
    const int nh = min(*hardcnt, HMAX);
    if (p * 16 >= nh) return;
    extern __shared__ float smem[];
    float* Hs = smem;                 // 32*USTR
    __shared__ float pl[32 * 17];
    __shared__ float wred[4][16];
    const int t = threadIdx.x;
#pragma unroll
    for (int r = 0; r < 64; ++r) {
        int idx = r * 256 + t;
        int jj = idx >> 9, k = idx & 511;
        Hs[jj * USTR + k] = h[(ll)(chunk * 32 + jj) * FIN + k];
    }
    const int u = t & 15, jl = t >> 4;
    const bool uvalid = (p * 16 + u) < nh;
    unsigned enc = rowmaxenc[p * 16 + u];
    unsigned ub = (enc & 0x80000000u) ? (enc & 0x7fffffffu) : ~enc;
    const float mx = __uint_as_float(ub);
    float psl = 0.f;
#pragma unroll
    for (int jb = 0; jb < 2; ++jb) {
        int jrow = jb * 16 + jl;
        int j = chunk * 32 + jrow;
        float ev = ebuf[(ll)j * HMAX + p * 16 + u];
        float pv = uvalid ? expf(ev - mx) : 0.f;
        pl[jrow * 17 + u] = pv;
        psl += pv;
    }
    psl += __shfl_xor(psl, 16, 64);
    psl += __shfl_xor(psl, 32, 64);
    if ((t & 63) < 16) wred[t >> 6][u] = psl;
    __syncthreads();   // covers Hs staging + pl writes + wred
    if (t < 16 && (p * 16 + t) < nh) {
        float s4 = (wred[0][t] + wred[1][t]) + (wred[2][t] + wred[3][t]);
        atomicAdd(&rowsum[p * 16 + t], s4);
    }
    // accumulate A[u][k] partials: thread (uu, w): k = 4w + 64m + c, m=0..7
    const int uu = t & 15, w = t >> 4;
    float4 acc[8];
#pragma unroll
    for (int m = 0; m < 8; ++m) acc[m] = make_float4(0.f, 0.f, 0.f, 0.f);
#pragma unroll 4
    for (int j = 0; j < 32; ++j) {
        float pv = pl[j * 17 + uu];
        const float* base = &Hs[j * USTR + 4 * w];
#pragma unroll
        for (int m = 0; m < 8; ++m) {
            float4 hv = *(const float4*)(base + 64 * m);
            acc[m].x = fmaf(pv, hv.x, acc[m].x);
            acc[m].y = fmaf(pv, hv.y, acc[m].y);
            acc[m].z = fmaf(pv, hv.z, acc[m].z);
            acc[m].w = fmaf(pv, hv.w, acc[m].w);
        }
    }
    float* gp = &gpart[((ll)chunk * HMAX + p * 16 + uu) * FIN + 4 * w];
#pragma unroll
    for (int m = 0; m < 8; ++m) *(float4*)(gp + 64 * m) = acc[m];
}

// ---------------- kernel 6d: reduce chunk partials ----------------
__global__ __launch_bounds__(256) void hardPreduce_kernel(
    const int* __restrict__ hardcnt, const float* __restrict__ gpart,
    float* __restrict__ hred) {
    const int slot = blockIdx.x;
    const int nh = min(*hardcnt, HMAX);
    if (slot >= nh) return;
    const int t = threadIdx.x;
    float s0 = 0.f, s1 = 0.f;
#pragma unroll 4
    for (int c = 0; c < 256; ++c) {
        float2 v = *(const float2*)&gpart[((ll)c * HMAX + slot) * FIN + 2 * t];
        s0 += v.x; s1 += v.y;
    }
    hred[slot * FIN + 2 * t] = s0;
    hred[slot * FIN + 2 * t + 1] = s1;
}

// ---------------- kernel 6e: project W^T(hred/ls), ELU, store ----------------
__global__ __launch_bounds__(256) void hardC_kernel(
    const float* __restrict__ W, const int* __restrict__ hardcnt,
    const int* __restrict__ hardlist, const float* __restrict__ rowsum,
    const float* __restrict__ hred, float* __restrict__ out) {
    const int hh = blockIdx.x;
    const int nh = min(*hardcnt, HMAX);
    if (hh >= nh) return;
    const int i = hardlist[hh];
    const int t = threadIdx.x;
    __shared__ float hl[FIN];
    float inv = 1.f / rowsum[hh];
    float2 hv = ((const float2*)&hred[hh * FIN])[t];
    hl[2 * t] = hv.x * inv;
    hl[2 * t + 1] = hv.y * inv;
    __syncthreads();
    float a = 0.f;
#pragma unroll 8
    for (int k = 0; k < FIN; ++k) a = fmaf(hl[k], W[k * FOUT + t], a);
    out[(ll)i * FOUT + t] = a > 0.f ? a : expm1f(a);
}

// ---------------- kernel 6f: serial overflow fallback (slot >= HMAX; normally no-op) ----------------
__global__ __launch_bounds__(256) void hardtail_kernel(
    const float* __restrict__ h, const float* __restrict__ W,
    const float* __restrict__ params, const int* __restrict__ adj,
    const float* __restrict__ x1, const float* __restrict__ x2,
    const float* __restrict__ w1, const float* __restrict__ w2,
    const int* __restrict__ hardcnt, const int* __restrict__ hardlist,
    float* __restrict__ out) {
    __shared__ float hl[FIN];
    __shared__ float vl[FOUT];
    __shared__ float uL[FIN];
    __shared__ float eb[N];        // 32 KB
    __shared__ float red[16];
    const int t = threadIdx.x;
    const int nh = *hardcnt;
    for (int hh = HMAX + blockIdx.x; hh < nh; hh += gridDim.x) {
        const int i = hardlist[hh];
        __syncthreads();
        ((float2*)hl)[t] = ((const float2*)&h[(ll)i * FIN])[t];
        __syncthreads();
        float a = 0.f;
        for (int k = 0; k < FIN; ++k) a = fmaf(hl[k], W[k * FOUT + t], a);
        vl[t] = a;
        __syncthreads();
        float u0 = 0.f, u1 = 0.f;
        for (int c = 0; c < FOUT; ++c) {
            float vc = vl[c];
            u0 = fmaf(W[t * FOUT + c], vc, u0);
            u1 = fmaf(W[(t + 256) * FOUT + c], vc, u1);
        }
        uL[t] = u0; uL[t + 256] = u1;
        __syncthreads();
        const float aC = params[0], cA = params[1], w1i = w1[i], w2i = w2[i];
        for (int j0 = 0; j0 < N; j0 += 256) {
            int j = j0 + t;
            const float* hr = &h[(ll)j * FIN];
            float s = 0.f;
            for (int k = 0; k < FIN; ++k) s = fmaf(hr[k], uL[k], s);
            float ev = fmaf(aC, s, cA);
            ev = fmaf(w1i, x1[j], ev);
            ev = fmaf(w2i, x2[j], ev);
            eb[j] = (adj[(ll)i * N + j] > 0) ? ev : NEGV;
        }
        __syncthreads();
        float mx = -INFINITY;
        for (int j = t; j < N; j += 256) mx = fmaxf(mx, eb[j]);
#pragma unroll
        for (int off = 1; off < 64; off <<= 1) mx = fmaxf(mx, __shfl_xor(mx, off, 64));
        if ((t & 63) == 0) red[t >> 6] = mx;
        __syncthreads();
        mx = fmaxf(fmaxf(red[0], red[1]), fmaxf(red[2], red[3]));
        float ls = 0.f;
        for (int j = t; j < N; j += 256) {
            float pv = expf(eb[j] - mx);
            eb[j] = pv;
            ls += pv;
        }
#pragma unroll
        for (int off = 1; off < 64; off <<= 1) ls += __shfl_xor(ls, off, 64);
        if ((t & 63) == 0) red[8 + (t >> 6)] = ls;
        __syncthreads();
        ls = (red[8] + red[9]) + (red[10] + red[11]);
        float s0 = 0.f, s1 = 0.f;
        for (int j = 0; j < N; ++j) {
            float pv = eb[j];
            s0 = fmaf(pv, h[(ll)j * FIN + 2 * t], s0);
            s1 = fmaf(pv, h[(ll)j * FIN + 2 * t + 1], s1);
        }
        __syncthreads();
        hl[2 * t] = s0 / ls;
        hl[2 * t + 1] = s1 / ls;
        __syncthreads();
        float o = 0.f;
        for (int k = 0; k < FIN; ++k) o = fmaf(hl[k], W[k * FOUT + t], o);
        out[(ll)i * FOUT + t] = o > 0.f ? o : expm1f(o);
    }
}

// ---------------- launch ----------------
extern "C" void kernel_launch(void* const* d_in, const int* in_sizes, int n_in,
                              void* d_out, int out_size, void* d_ws, size_t ws_size,
                              hipStream_t stream) {
    const float* h   = (const float*)d_in[0];
    const float* W   = (const float*)d_in[1];
    const float* Mui = (const float*)d_in[2];
    const int*   adj = (const int*)d_in[3];
    float* out = (float*)d_out;

    float* ws = (float*)d_ws;
    // big, alignment-sensitive arrays first (offsets stay multiples of 4 floats)
    float* ebuf   = ws;                          // N*HMAX          = 524288
    float* gpart  = ebuf + (ll)N * HMAX;         // 256*HMAX*FIN    = 8388608
    float* hred   = gpart + (ll)256 * HMAX * FIN;// HMAX*FIN        = 32768
    float* uarr   = hred + HMAX * FIN;           // HMAX*FIN        = 32768
    float* t1a    = uarr + HMAX * FIN;           // N
    float* x1     = t1a + N;
    float* x2     = x1 + N;
    float* w1     = x2 + N;
    float* w2     = w1 + N;
    float* hn     = w2 + N;
    float* wcol1  = hn + N;                      // 512
    float* celu   = wcol1 + FIN;                 // NCAND*FOUT = 4096
    float* o1v    = celu + NCAND * FOUT;         // 1024
    float* ct1    = o1v + 1024;                  // 16
    float* cx1    = ct1 + NCAND;
    float* cx2    = cx1 + NCAND;
    float* ubx    = cx2 + NCAND;                 // 2
    float* params = ubx + 2;                     // 8
    float* wfrob2 = params + 8;                  // 1
    float* rowsum = wfrob2 + 1;                  // HMAX
    float* fend   = rowsum + HMAX;
    int*   o1i       = (int*)(fend + 4);         // 1024
    int*   cidx      = o1i + 1024;               // 16
    int*   hardcnt   = cidx + NCAND;             // 1
    unsigned* hnmaxb = (unsigned*)(hardcnt + 1); // 1
    unsigned* rowmaxenc = hnmaxb + 1;            // HMAX
    int*   hardlist  = (int*)(rowmaxenc + HMAX); // N

    params_kernel<<<1, 64, 0, stream>>>(Mui, params, wfrob2, hnmaxb);
    wfrob_kernel<<<FIN * FOUT / 1024, 256, 0, stream>>>(W, wfrob2, wcol1);
    rowstats_kernel<<<N / 4, 256, 0, stream>>>(h, params, wcol1, t1a, x1, x2, w1, w2,
                                               hn, hnmaxb);
    topk1_kernel<<<64, 64, 0, stream>>>(t1a, o1v, o1i);
    topk2_kernel<<<1, 1024, 0, stream>>>(o1v, o1i, t1a, x1, x2,
                                         cidx, ct1, cx1, cx2, ubx, hardcnt);
    candwh_kernel<<<NCAND, 256, 0, stream>>>(h, W, cidx, celu);
    hardinit_kernel<<<HMAX, 256, 0, stream>>>(uarr, rowsum, rowmaxenc);
    classify_kernel<<<N / 4, 256, 0, stream>>>(params, adj, cidx, ct1, cx1, cx2, ubx,
                                               w1, w2, hn, wfrob2, hnmaxb, celu,
                                               hardcnt, hardlist, out);
    hardprep_kernel<<<HMAX, 256, 0, stream>>>(h, W, hardcnt, hardlist, uarr);

    const int smemS = 2 * 16 * USTR * sizeof(float);   // 66 KB
    const int smemP = 32 * USTR * sizeof(float);       // 66 KB
    hipFuncSetAttribute((const void*)hardS_kernel,
                        hipFuncAttributeMaxDynamicSharedMemorySize, smemS);
    hipFuncSetAttribute((const void*)hardP_kernel,
                        hipFuncAttributeMaxDynamicSharedMemorySize, smemP);
    hardS_kernel<<<1024, 256, smemS, stream>>>(h, params, adj, x1, x2, w1, w2,
                                               hardcnt, hardlist, uarr, ebuf, rowmaxenc);
    hardP_kernel<<<1024, 256, smemP, stream>>>(h, hardcnt, ebuf, rowmaxenc, rowsum, gpart);
    hardPreduce_kernel<<<HMAX, 256, 0, stream>>>(hardcnt, gpart, hred);
    hardC_kernel<<<HMAX, 256, 0, stream>>>(W, hardcnt, hardlist, rowsum, hred, out);
    hardtail_kernel<<<64, 256, 0, stream>>>(h, W, params, adj, x1, x2, w1, w2,
                                            hardcnt, hardlist, out);
    (void)n_in; (void)in_sizes; (void)out_size; (void)ws_size;
}

// Round 7
// 514.596 us; speedup vs baseline: 1.1165x; 1.1165x over previous
//
#include <hip/hip_runtime.h>
#include <math.h>

#define N 8192
#define FIN 512
#define FOUT 256
#define NEGV (-9e15f)
#define NCAND 16
#define HMAX 16

typedef long long ll;

// ---------------- kernel 0: mui softmax + derived params (+zero ctrl) ----------------
__global__ void params_kernel(const float* __restrict__ Mui, float* __restrict__ params,
                              unsigned* __restrict__ gmaxbits) {
    if (threadIdx.x == 0) {
        float m = Mui[0];
        for (int i = 1; i < 6; ++i) m = fmaxf(m, Mui[i]);
        float e[6], s = 0.f;
        for (int i = 0; i < 6; ++i) { e[i] = expf(Mui[i] - m); s += e[i]; }
        float mui[6];
        for (int i = 0; i < 6; ++i) mui[i] = e[i] / s;
        params[0] = mui[0] + mui[1] + mui[2] + mui[3];                    // a (G coefficient)
        params[1] = 0.5f * (mui[0] + mui[1]) + 1.0f * (mui[2] + mui[3]); // additive const
        params[2] = 256.0f * mui[4];                                      // D*mui4
        params[3] = 256.0f * mui[5];                                      // D*mui5
        *gmaxbits = 0u;                                                   // re-init every call
    }
}

// ---------------- kernel 1: Wh = h @ W  (8192x512x256 f32) ----------------
#define GK 16
__global__ __launch_bounds__(256) void wh_gemm(const float* __restrict__ A,
                                               const float* __restrict__ B,
                                               float* __restrict__ C) {
    __shared__ float As[GK][68];
    __shared__ float Bs[GK][68];
    const int tid = threadIdx.x;
    const int m0 = blockIdx.y * 64, n0 = blockIdx.x * 64;
    const int tx = tid & 15, ty = tid >> 4;
    const int arow = tid >> 2, akk = (tid & 3) * 4;
    const int brow = tid >> 4, bnn = (tid & 15) * 4;
    float acc[4][4] = {};
    for (int k0 = 0; k0 < FIN; k0 += GK) {
        float4 av = *(const float4*)&A[(m0 + arow) * FIN + k0 + akk];
        float4 bv = *(const float4*)&B[(k0 + brow) * FOUT + n0 + bnn];
        As[akk + 0][arow] = av.x; As[akk + 1][arow] = av.y;
        As[akk + 2][arow] = av.z; As[akk + 3][arow] = av.w;
        *(float4*)&Bs[brow][bnn] = bv;
        __syncthreads();
#pragma unroll
        for (int k = 0; k < GK; ++k) {
            float4 a = *(const float4*)&As[k][4 * ty];
            float4 b = *(const float4*)&Bs[k][4 * tx];
            float ar[4] = {a.x, a.y, a.z, a.w};
            float br[4] = {b.x, b.y, b.z, b.w};
#pragma unroll
            for (int i = 0; i < 4; ++i)
#pragma unroll
                for (int j = 0; j < 4; ++j)
                    acc[i][j] = fmaf(ar[i], br[j], acc[i][j]);
        }
        __syncthreads();
    }
#pragma unroll
    for (int i = 0; i < 4; ++i) {
        float4 v = make_float4(acc[i][0], acc[i][1], acc[i][2], acc[i][3]);
        *(float4*)&C[(m0 + 4 * ty + i) * FOUT + n0 + 4 * tx] = v;
    }
}

// ---------------- kernel 2: per-row factors, t1, row norms, global max norm ----------------
__global__ __launch_bounds__(64) void factors2_kernel(
    const float* __restrict__ Wh, const float* __restrict__ params,
    float* __restrict__ t1a, float* __restrict__ x1, float* __restrict__ x2,
    float* __restrict__ w1, float* __restrict__ w2,
    float* __restrict__ nrm, unsigned* __restrict__ gmaxbits) {
    int i = blockIdx.x;
    int l = threadIdx.x;
    float4 v = ((const float4*)&Wh[i * FOUT])[l];
    float s = v.x * v.x + v.y * v.y + v.z * v.z + v.w * v.w;
#pragma unroll
    for (int off = 1; off < 64; off <<= 1) s += __shfl_xor(s, off, 64);
    if (l == 0) {
        float nr = sqrtf(s);
        nrm[i] = nr;
        atomicMax(gmaxbits, __float_as_uint(nr));   // nr > 0 -> bit-monotone
        float t = Wh[i * FOUT + 1];
        float t1 = t * t;                            // exact same expr as verified R2 kernel
        t1a[i] = t1;
        x1[i] = expf(0.5f * t1);
        x2[i] = expf(t1);
        w1[i] = params[2] * expf(-0.5f * t1);
        w2[i] = params[3] * expf(-t1);
    }
}

// ---------------- kernel 3a: per-slice top-16 (64 blocks x 128 rows, 1 wave) ----------------
__global__ __launch_bounds__(64) void topk1_kernel(const float* __restrict__ t1a,
                                                   float* __restrict__ o1v,
                                                   int* __restrict__ o1i) {
    const int l = threadIdx.x;
    const int base = blockIdx.x * 128;
    float v0 = t1a[base + l], v1 = t1a[base + 64 + l];
    int i0 = base + l, i1 = base + 64 + l;
    for (int r = 0; r < NCAND; ++r) {
        float mv; int mi;
        if (v0 >= v1) { mv = v0; mi = i0; } else { mv = v1; mi = i1; }
#pragma unroll
        for (int off = 1; off < 64; off <<= 1) {
            float ov = __shfl_xor(mv, off, 64);
            int   oi = __shfl_xor(mi, off, 64);
            if (ov > mv || (ov == mv && oi < mi)) { mv = ov; mi = oi; }
        }
        if (mi == i0) v0 = -2.f;
        if (mi == i1) v1 = -2.f;
        if (l == r) { o1v[blockIdx.x * NCAND + r] = mv; o1i[blockIdx.x * NCAND + r] = mi; }
    }
}

// ---------------- kernel 3b: global top-16 from 1024 candidates (1 block) ----------------
__global__ __launch_bounds__(1024) void topk2_kernel(
    const float* __restrict__ o1v, const int* __restrict__ o1i,
    const float* __restrict__ t1a, const float* __restrict__ x1, const float* __restrict__ x2,
    int* __restrict__ cidx, float* __restrict__ ct1, float* __restrict__ cx1,
    float* __restrict__ cx2, float* __restrict__ ubx, int* __restrict__ hardcnt) {
    __shared__ float lv[16];
    __shared__ int li[16];
    __shared__ float bvs;
    __shared__ int bis;
    const int t = threadIdx.x;
    float v = o1v[t];
    int idx = o1i[t];
    for (int r = 0; r < NCAND; ++r) {
        float mv = v; int mi = idx;
#pragma unroll
        for (int off = 1; off < 64; off <<= 1) {
            float ov = __shfl_xor(mv, off, 64);
            int   oi = __shfl_xor(mi, off, 64);
            if (ov > mv || (ov == mv && oi < mi)) { mv = ov; mi = oi; }
        }
        if ((t & 63) == 0) { lv[t >> 6] = mv; li[t >> 6] = mi; }
        __syncthreads();
        if (t < 64) {
            float m2 = (t < 16) ? lv[t] : -3.f;
            int   i2 = (t < 16) ? li[t] : -1;
#pragma unroll
            for (int off = 1; off < 16; off <<= 1) {
                float ov = __shfl_xor(m2, off, 64);
                int   oi = __shfl_xor(i2, off, 64);
                if (ov > m2 || (ov == m2 && oi < i2)) { m2 = ov; i2 = oi; }
            }
            if (t == 0) { bvs = m2; bis = i2; }
        }
        __syncthreads();
        if (idx == bis) v = -2.f;
        if (t == r) cidx[r] = bis;
    }
    __syncthreads();
    if (t < NCAND) {
        int j = cidx[t];
        ct1[t] = t1a[j];
        cx1[t] = x1[j];
        cx2[t] = x2[j];
    }
    if (t == 0) {
        int j = cidx[NCAND - 1];
        ubx[0] = x1[j];
        ubx[1] = x2[j];
        *hardcnt = 0;
    }
}

// ---------------- kernel 3c: init hard-row accumulators ----------------
__global__ __launch_bounds__(256) void hardinit_kernel(float* __restrict__ acc,
                                                       float* __restrict__ rowsum,
                                                       unsigned* __restrict__ rowmaxenc) {
    int b = blockIdx.x, t = threadIdx.x;
    acc[b * FOUT + t] = 0.f;
    if (t == 0) { rowsum[b] = 0.f; rowmaxenc[b] = 0u; }
}

// ---------------- kernel 4: classify rows; write easy rows (one wave per row) ----------------
__global__ __launch_bounds__(256) void classify_kernel(
    const float* __restrict__ Wh, const float* __restrict__ params,
    const int* __restrict__ adj, const int* __restrict__ cidx,
    const float* __restrict__ ct1, const float* __restrict__ cx1, const float* __restrict__ cx2,
    const float* __restrict__ ubx, const float* __restrict__ w1, const float* __restrict__ w2,
    const float* __restrict__ nrm, const unsigned* __restrict__ gmaxbits,
    int* __restrict__ hardcnt, int* __restrict__ hardlist, float* __restrict__ out) {
    const int i = (blockIdx.x << 2) + (threadIdx.x >> 6);   // one 64-lane wave per row
    const int lane = threadIdx.x & 63;
    const bool valid = lane < NCAND;

    int   cj  = valid ? cidx[lane] : 0;
    float cT  = valid ? ct1[lane] : -1.f;
    float cX1 = valid ? cx1[lane] : 0.f;
    float cX2 = valid ? cx2[lane] : 0.f;
    int ad = valid ? adj[(ll)i * N + cj] : 0;
    unsigned long long m = __ballot(ad > 0);

    float w1i = w1[i], w2i = w2[i];
    bool hard = false;
    int j1 = -1;
    if (m == 0ull) {
        hard = true;   // no adjacent candidate (incl. all-zero adj row) -> exact fallback
    } else {
        int f = __ffsll(m) - 1;
        j1 = __shfl(cj, f, 64);
        float t1f = __shfl(cT, f, 64);
        float x1f = __shfl(cX1, f, 64);
        float x2f = __shfl(cX2, f, 64);
        float lastT = __shfl(cT, NCAND - 1, 64);
        // tie on t1 bits among adjacent candidates -> reference may average -> fallback;
        // tie with the candidate-list boundary value -> off-list tie possible -> fallback
        unsigned long long tm = __ballot(ad > 0 && (cT == t1f));
        if (__popcll(tm) > 1 || t1f == lastT) hard = true;
        float Lx1 = w1i * x1f + w2i * x2f;
        unsigned long long m2 = m & ~(1ull << f);
        float Lx2 = -INFINITY;
        if (m2 != 0ull) {
            int s2 = __ffsll(m2) - 1;
            Lx2 = w1i * __shfl(cX1, s2, 64) + w2i * __shfl(cX2, s2, 64);
        }
        float ub  = w1i * ubx[0] + w2i * ubx[1];   // bound for ALL non-candidate columns
        float alt = fmaxf(Lx2, ub);
        float gmax = __uint_as_float(*gmaxbits);
        // |a*G| <= a*|Wh_i|*|Wh_j| both sides; + slack for f32 rounding & our-vs-ref exp diffs
        float margin = 2.0f * params[0] * nrm[i] * gmax + 100.0f + 1e-5f * Lx1;
        if (!(Lx1 - alt > margin)) hard = true;    // NaN-safe: NaN -> hard
    }
    if (hard) {
        if (lane == 0) { int p = atomicAdd(hardcnt, 1); hardlist[p] = i; }
        return;
    }
    // easy: softmax is exactly one-hot at j1 -> out = ELU(Wh[j1])
    float4 v = ((const float4*)&Wh[(ll)j1 * FOUT])[lane];
    v.x = v.x > 0.f ? v.x : expm1f(v.x);
    v.y = v.y > 0.f ? v.y : expm1f(v.y);
    v.z = v.z > 0.f ? v.z : expm1f(v.z);
    v.w = v.w > 0.f ? v.w : expm1f(v.w);
    ((float4*)&out[(ll)i * FOUT])[lane] = v;
}

// ---------------- kernel 5a: hard rows — logits + row max (parallel over chunks) ----------------
__global__ __launch_bounds__(256) void hardA_kernel(
    const float* __restrict__ Wh, const float* __restrict__ params,
    const int* __restrict__ adj, const float* __restrict__ x1, const float* __restrict__ x2,
    const float* __restrict__ w1, const float* __restrict__ w2,
    const int* __restrict__ hardcnt, const int* __restrict__ hardlist,
    float* __restrict__ ebuf, unsigned* __restrict__ rowmaxenc) {
    const int h = blockIdx.x >> 5;          // 32 chunks of 256 columns
    const int chunk = blockIdx.x & 31;
    const int nh = min(*hardcnt, HMAX);
    if (h >= nh) return;
    const int i = hardlist[h];
    __shared__ float Whi[FOUT];
    __shared__ float red[4];
    const int t = threadIdx.x;
    Whi[t] = Wh[(ll)i * FOUT + t];
    __syncthreads();
    const int j = (chunk << 8) + t;
    const float4* wi4 = (const float4*)Whi;
    const float4* wr  = (const float4*)&Wh[(ll)j * FOUT];
    float s = 0.f;
#pragma unroll 8
    for (int f = 0; f < 64; ++f) {
        float4 a = wi4[f], b = wr[f];
        s = fmaf(a.x, b.x, fmaf(a.y, b.y, fmaf(a.z, b.z, fmaf(a.w, b.w, s))));
    }
    // EXACT same logit assembly as the verified R2 kernel
    float ev = fmaf(params[0], s, params[1]);
    ev = fmaf(w1[i], x1[j], ev);
    ev = fmaf(w2[i], x2[j], ev);
    ev = (adj[(ll)i * N + j] > 0) ? ev : NEGV;
    ebuf[h * N + j] = ev;
    float mx = ev;
#pragma unroll
    for (int off = 1; off < 64; off <<= 1) mx = fmaxf(mx, __shfl_xor(mx, off, 64));
    if ((t & 63) == 0) red[t >> 6] = mx;
    __syncthreads();
    if (t == 0) {
        mx = fmaxf(fmaxf(red[0], red[1]), fmaxf(red[2], red[3]));
        unsigned u = __float_as_uint(mx);
        unsigned enc = (u & 0x80000000u) ? ~u : (u | 0x80000000u);
        atomicMax(&rowmaxenc[h], enc);
    }
}

// ---------------- kernel 5b: hard rows — exp/sum + partial PV ----------------
__global__ __launch_bounds__(256) void hardB_kernel(
    const float* __restrict__ Wh, const int* __restrict__ hardcnt,
    const float* __restrict__ ebuf, const unsigned* __restrict__ rowmaxenc,
    float* __restrict__ rowsum, float* __restrict__ acc) {
    const int h = blockIdx.x >> 5;
    const int chunk = blockIdx.x & 31;
    const int nh = min(*hardcnt, HMAX);
    if (h >= nh) return;
    const int t = threadIdx.x;
    unsigned enc = rowmaxenc[h];
    unsigned u = (enc & 0x80000000u) ? (enc & 0x7fffffffu) : ~enc;
    const float mx = __uint_as_float(u);
    const int j = (chunk << 8) + t;
    float p = expf(ebuf[h * N + j] - mx);
    __shared__ float pl[256];
    pl[t] = p;
    float ps = p;
#pragma unroll
    for (int off = 1; off < 64; off <<= 1) ps += __shfl_xor(ps, off, 64);
    if ((t & 63) == 0) atomicAdd(&rowsum[h], ps);
    __syncthreads();
    float o = 0.f;
    const float* base = &Wh[(ll)(chunk << 8) * FOUT + t];
#pragma unroll 4
    for (int jj = 0; jj < 256; ++jj) o = fmaf(pl[jj], base[(ll)jj * FOUT], o);
    atomicAdd(&acc[h * FOUT + t], o);
}

// ---------------- kernel 5c: hard rows — normalize + ELU + store ----------------
__global__ __launch_bounds__(256) void hardC_kernel(
    const int* __restrict__ hardcnt, const int* __restrict__ hardlist,
    const float* __restrict__ rowsum, const float* __restrict__ acc,
    float* __restrict__ out) {
    const int h = blockIdx.x;
    const int nh = min(*hardcnt, HMAX);
    if (h >= nh) return;
    const int i = hardlist[h];
    const int t = threadIdx.x;
    float o = acc[h * FOUT + t] / rowsum[h];
    out[(ll)i * FOUT + t] = o > 0.f ? o : expm1f(o);
}

// ---------------- kernel 5d: serial overflow fallback (h >= HMAX; normally no-op) ----------------
__global__ __launch_bounds__(256) void hardtail_kernel(
    const float* __restrict__ Wh, const float* __restrict__ params,
    const int* __restrict__ adj, const float* __restrict__ x1, const float* __restrict__ x2,
    const float* __restrict__ w1, const float* __restrict__ w2,
    const int* __restrict__ hardcnt, const int* __restrict__ hardlist,
    float* __restrict__ out) {
    __shared__ float Whi[FOUT];
    __shared__ float ebuf[N];
    __shared__ float red[16];
    const int t = threadIdx.x;
    const int nh = *hardcnt;
    for (int h = HMAX + blockIdx.x; h < nh; h += gridDim.x) {
        const int i = hardlist[h];
        __syncthreads();
        Whi[t] = Wh[(ll)i * FOUT + t];
        __syncthreads();
        const float aC = params[0], cA = params[1], w1i = w1[i], w2i = w2[i];
        const float4* wi4 = (const float4*)Whi;
        for (int j0 = 0; j0 < N; j0 += 256) {
            int j = j0 + t;
            const float4* wr = (const float4*)&Wh[(ll)j * FOUT];
            float s = 0.f;
#pragma unroll 8
            for (int f = 0; f < 64; ++f) {
                float4 a = wi4[f], b = wr[f];
                s = fmaf(a.x, b.x, fmaf(a.y, b.y, fmaf(a.z, b.z, fmaf(a.w, b.w, s))));
            }
            float ev = fmaf(aC, s, cA);
            ev = fmaf(w1i, x1[j], ev);
            ev = fmaf(w2i, x2[j], ev);
            ebuf[j] = (adj[(ll)i * N + j] > 0) ? ev : NEGV;
        }
        __syncthreads();
        float mx = -INFINITY;
        for (int j = t; j < N; j += 256) mx = fmaxf(mx, ebuf[j]);
#pragma unroll
        for (int off = 1; off < 64; off <<= 1) mx = fmaxf(mx, __shfl_xor(mx, off, 64));
        if ((t & 63) == 0) red[t >> 6] = mx;
        __syncthreads();
        mx = fmaxf(fmaxf(red[0], red[1]), fmaxf(red[2], red[3]));
        float ls = 0.f;
        for (int j = t; j < N; j += 256) {
            float p = expf(ebuf[j] - mx);
            ebuf[j] = p;
            ls += p;
        }
#pragma unroll
        for (int off = 1; off < 64; off <<= 1) ls += __shfl_xor(ls, off, 64);
        if ((t & 63) == 0) red[8 + (t >> 6)] = ls;
        __syncthreads();
        ls = (red[8] + red[9]) + (red[10] + red[11]);
        float o0 = 0.f, o1 = 0.f, o2 = 0.f, o3 = 0.f;
        for (int j = 0; j < N; j += 4) {
            o0 = fmaf(ebuf[j + 0], Wh[(ll)(j + 0) * FOUT + t], o0);
            o1 = fmaf(ebuf[j + 1], Wh[(ll)(j + 1) * FOUT + t], o1);
            o2 = fmaf(ebuf[j + 2], Wh[(ll)(j + 2) * FOUT + t], o2);
            o3 = fmaf(ebuf[j + 3], Wh[(ll)(j + 3) * FOUT + t], o3);
        }
        float o = ((o0 + o1) + (o2 + o3)) / ls;
        out[(ll)i * FOUT + t] = o > 0.f ? o : expm1f(o);
    }
}

// ---------------- launch ----------------
extern "C" void kernel_launch(void* const* d_in, const int* in_sizes, int n_in,
                              void* d_out, int out_size, void* d_ws, size_t ws_size,
                              hipStream_t stream) {
    const float* h   = (const float*)d_in[0];
    const float* W   = (const float*)d_in[1];
    const float* Mui = (const float*)d_in[2];
    const int*   adj = (const int*)d_in[3];
    float* out = (float*)d_out;

    float* ws = (float*)d_ws;
    float* Wh     = ws;                         // 8192*256
    float* t1a    = Wh + N * FOUT;              // N
    float* x1     = t1a + N;
    float* x2     = x1 + N;
    float* w1     = x2 + N;
    float* w2     = w1 + N;
    float* nrm    = w2 + N;
    float* params = nrm + N;                    // 8
    float* ct1    = params + 8;                 // NCAND
    float* cx1    = ct1 + NCAND;
    float* cx2    = cx1 + NCAND;
    float* ubx    = cx2 + NCAND;                // 2
    float* o1v    = ubx + 2;                    // 1024
    float* ebuf   = o1v + 1024;                 // HMAX*N
    float* acc    = ebuf + HMAX * N;            // HMAX*FOUT
    float* rowsum = acc + HMAX * FOUT;          // HMAX
    int*   o1i       = (int*)(rowsum + HMAX);   // 1024
    int*   cidx      = o1i + 1024;              // NCAND
    int*   hardcnt   = cidx + NCAND;            // 1
    unsigned* gmaxb  = (unsigned*)(hardcnt + 1);// 1
    unsigned* rowmaxenc = gmaxb + 1;            // HMAX
    int*   hardlist  = (int*)(rowmaxenc + HMAX);// N

    params_kernel<<<1, 64, 0, stream>>>(Mui, params, gmaxb);
    wh_gemm<<<dim3(FOUT / 64, N / 64), 256, 0, stream>>>(h, W, Wh);
    factors2_kernel<<<N, 64, 0, stream>>>(Wh, params, t1a, x1, x2, w1, w2, nrm, gmaxb);
    topk1_kernel<<<64, 64, 0, stream>>>(t1a, o1v, o1i);
    topk2_kernel<<<1, 1024, 0, stream>>>(o1v, o1i, t1a, x1, x2,
                                         cidx, ct1, cx1, cx2, ubx, hardcnt);
    hardinit_kernel<<<HMAX, 256, 0, stream>>>(acc, rowsum, rowmaxenc);
    classify_kernel<<<N / 4, 256, 0, stream>>>(Wh, params, adj, cidx, ct1, cx1, cx2, ubx,
                                               w1, w2, nrm, gmaxb, hardcnt, hardlist, out);
    hardA_kernel<<<32 * HMAX, 256, 0, stream>>>(Wh, params, adj, x1, x2, w1, w2,
                                                hardcnt, hardlist, ebuf, rowmaxenc);
    hardB_kernel<<<32 * HMAX, 256, 0, stream>>>(Wh, hardcnt, ebuf, rowmaxenc, rowsum, acc);
    hardC_kernel<<<HMAX, 256, 0, stream>>>(hardcnt, hardlist, rowsum, acc, out);
    hardtail_kernel<<<128, 256, 0, stream>>>(Wh, params, adj, x1, x2, w1, w2,
                                             hardcnt, hardlist, out);
    (void)n_in; (void)in_sizes; (void)out_size; (void)ws_size;
}

// Round 8
// 508.995 us; speedup vs baseline: 1.1288x; 1.0110x over previous
//
#include <hip/hip_runtime.h>
#include <math.h>

#define N 8192
#define FIN 512
#define FOUT 256
#define NEGV (-9e15f)
#define NCAND 16
#define HMAX 16

typedef long long ll;

// ---------------- kernel 1: Wh = h @ W (8192x512x256 f32), double-buffered ----------------
// GK=32, register prefetch of next tile between barriers; also zeroes gmaxbits (runs
// before factors2 in stream order).
__global__ __launch_bounds__(256) void wh_gemm(const float* __restrict__ A,
                                               const float* __restrict__ B,
                                               float* __restrict__ C,
                                               unsigned* __restrict__ gmaxbits) {
    __shared__ float As[32][68];
    __shared__ float Bs[32][68];
    const int tid = threadIdx.x;
    if (blockIdx.x == 0 && blockIdx.y == 0 && tid == 0) *gmaxbits = 0u;
    const int m0 = blockIdx.y * 64, n0 = blockIdx.x * 64;
    const int tx = tid & 15, ty = tid >> 4;
    const int arow = tid >> 2, ak = (tid & 3) * 8;   // A: 64 rows x 32 k
    const int brow = tid >> 3, bn = (tid & 7) * 8;   // B: 32 k x 64 n
    const float* aptr = &A[(m0 + arow) * FIN + ak];
    const float* bptr = &B[brow * FOUT + n0 + bn];
    float4 av0 = *(const float4*)aptr, av1 = *(const float4*)(aptr + 4);
    float4 bv0 = *(const float4*)bptr, bv1 = *(const float4*)(bptr + 4);
    float acc[4][4] = {};
    for (int k0 = 0; k0 < FIN; k0 += 32) {
        As[ak + 0][arow] = av0.x; As[ak + 1][arow] = av0.y;
        As[ak + 2][arow] = av0.z; As[ak + 3][arow] = av0.w;
        As[ak + 4][arow] = av1.x; As[ak + 5][arow] = av1.y;
        As[ak + 6][arow] = av1.z; As[ak + 7][arow] = av1.w;
        *(float4*)&Bs[brow][bn] = bv0;
        *(float4*)&Bs[brow][bn + 4] = bv1;
        __syncthreads();
        if (k0 + 32 < FIN) {   // prefetch next tile while this one computes
            aptr += 32; bptr += 32 * FOUT;
            av0 = *(const float4*)aptr; av1 = *(const float4*)(aptr + 4);
            bv0 = *(const float4*)bptr; bv1 = *(const float4*)(bptr + 4);
        }
#pragma unroll
        for (int k = 0; k < 32; ++k) {
            float4 a = *(const float4*)&As[k][4 * ty];
            float4 b = *(const float4*)&Bs[k][4 * tx];
            float ar[4] = {a.x, a.y, a.z, a.w};
            float br[4] = {b.x, b.y, b.z, b.w};
#pragma unroll
            for (int i = 0; i < 4; ++i)
#pragma unroll
                for (int j = 0; j < 4; ++j)
                    acc[i][j] = fmaf(ar[i], br[j], acc[i][j]);
        }
        __syncthreads();
    }
#pragma unroll
    for (int i = 0; i < 4; ++i) {
        float4 v = make_float4(acc[i][0], acc[i][1], acc[i][2], acc[i][3]);
        *(float4*)&C[(m0 + 4 * ty + i) * FOUT + n0 + 4 * tx] = v;
    }
}

// ---------------- kernel 2: per-row factors + t1 + norms; block 0 publishes params ----------------
__global__ __launch_bounds__(64) void factors2_kernel(
    const float* __restrict__ Wh, const float* __restrict__ Mui,
    float* __restrict__ params,
    float* __restrict__ t1a, float* __restrict__ x1, float* __restrict__ x2,
    float* __restrict__ w1, float* __restrict__ w2,
    float* __restrict__ nrm, unsigned* __restrict__ gmaxbits) {
    int i = blockIdx.x;
    int l = threadIdx.x;
    float4 v = ((const float4*)&Wh[i * FOUT])[l];
    float s = v.x * v.x + v.y * v.y + v.z * v.z + v.w * v.w;
#pragma unroll
    for (int off = 1; off < 64; off <<= 1) s += __shfl_xor(s, off, 64);
    if (l == 0) {
        // recompute mui softmax in-register (identical expressions to verified R2 path)
        float m = Mui[0];
        for (int q = 1; q < 6; ++q) m = fmaxf(m, Mui[q]);
        float e[6], es = 0.f;
        for (int q = 0; q < 6; ++q) { e[q] = expf(Mui[q] - m); es += e[q]; }
        float mui[6];
        for (int q = 0; q < 6; ++q) mui[q] = e[q] / es;
        float p2 = 256.0f * mui[4], p3 = 256.0f * mui[5];
        if (i == 0) {
            params[0] = mui[0] + mui[1] + mui[2] + mui[3];
            params[1] = 0.5f * (mui[0] + mui[1]) + 1.0f * (mui[2] + mui[3]);
            params[2] = p2;
            params[3] = p3;
        }
        float nr = sqrtf(s);
        nrm[i] = nr;
        atomicMax(gmaxbits, __float_as_uint(nr));   // nr > 0 -> bit-monotone
        float t = Wh[i * FOUT + 1];
        float t1 = t * t;                            // exact same expr as verified R2 kernel
        t1a[i] = t1;
        x1[i] = expf(0.5f * t1);
        x2[i] = expf(t1);
        w1[i] = p2 * expf(-0.5f * t1);
        w2[i] = p3 * expf(-t1);
    }
}

// ---------------- kernel 3a: per-slice top-16 (64 blocks x 128 rows, 1 wave) ----------------
__global__ __launch_bounds__(64) void topk1_kernel(const float* __restrict__ t1a,
                                                   float* __restrict__ o1v,
                                                   int* __restrict__ o1i) {
    const int l = threadIdx.x;
    const int base = blockIdx.x * 128;
    float v0 = t1a[base + l], v1 = t1a[base + 64 + l];
    int i0 = base + l, i1 = base + 64 + l;
    for (int r = 0; r < NCAND; ++r) {
        float mv; int mi;
        if (v0 >= v1) { mv = v0; mi = i0; } else { mv = v1; mi = i1; }
#pragma unroll
        for (int off = 1; off < 64; off <<= 1) {
            float ov = __shfl_xor(mv, off, 64);
            int   oi = __shfl_xor(mi, off, 64);
            if (ov > mv || (ov == mv && oi < mi)) { mv = ov; mi = oi; }
        }
        if (mi == i0) v0 = -2.f;
        if (mi == i1) v1 = -2.f;
        if (l == r) { o1v[blockIdx.x * NCAND + r] = mv; o1i[blockIdx.x * NCAND + r] = mi; }
    }
}

// ---------------- kernel 3b: global top-16 + init hard accumulators (1 block) ----------------
__global__ __launch_bounds__(1024) void topk2_kernel(
    const float* __restrict__ o1v, const int* __restrict__ o1i,
    const float* __restrict__ t1a, const float* __restrict__ x1, const float* __restrict__ x2,
    int* __restrict__ cidx, float* __restrict__ ct1, float* __restrict__ cx1,
    float* __restrict__ cx2, float* __restrict__ ubx, int* __restrict__ hardcnt,
    float* __restrict__ acc, float* __restrict__ rowsum, unsigned* __restrict__ rowmaxenc) {
    __shared__ float lv[16];
    __shared__ int li[16];
    __shared__ float bvs;
    __shared__ int bis;
    const int t = threadIdx.x;
    // init hard-row accumulators (HMAX*FOUT = 4096)
#pragma unroll
    for (int q = 0; q < HMAX * FOUT / 1024; ++q) acc[q * 1024 + t] = 0.f;
    if (t < HMAX) { rowsum[t] = 0.f; rowmaxenc[t] = 0u; }
    float v = o1v[t];
    int idx = o1i[t];
    for (int r = 0; r < NCAND; ++r) {
        float mv = v; int mi = idx;
#pragma unroll
        for (int off = 1; off < 64; off <<= 1) {
            float ov = __shfl_xor(mv, off, 64);
            int   oi = __shfl_xor(mi, off, 64);
            if (ov > mv || (ov == mv && oi < mi)) { mv = ov; mi = oi; }
        }
        if ((t & 63) == 0) { lv[t >> 6] = mv; li[t >> 6] = mi; }
        __syncthreads();
        if (t < 64) {
            float m2 = (t < 16) ? lv[t] : -3.f;
            int   i2 = (t < 16) ? li[t] : -1;
#pragma unroll
            for (int off = 1; off < 16; off <<= 1) {
                float ov = __shfl_xor(m2, off, 64);
                int   oi = __shfl_xor(i2, off, 64);
                if (ov > m2 || (ov == m2 && oi < i2)) { m2 = ov; i2 = oi; }
            }
            if (t == 0) { bvs = m2; bis = i2; }
        }
        __syncthreads();
        if (idx == bis) v = -2.f;
        if (t == r) cidx[r] = bis;
    }
    __syncthreads();
    if (t < NCAND) {
        int j = cidx[t];
        ct1[t] = t1a[j];
        cx1[t] = x1[j];
        cx2[t] = x2[j];
    }
    if (t == 0) {
        int j = cidx[NCAND - 1];
        ubx[0] = x1[j];
        ubx[1] = x2[j];
        *hardcnt = 0;
    }
}

// ---------------- kernel 4: classify rows; write easy rows (one wave per row) ----------------
__global__ __launch_bounds__(256) void classify_kernel(
    const float* __restrict__ Wh, const float* __restrict__ params,
    const int* __restrict__ adj, const int* __restrict__ cidx,
    const float* __restrict__ ct1, const float* __restrict__ cx1, const float* __restrict__ cx2,
    const float* __restrict__ ubx, const float* __restrict__ w1, const float* __restrict__ w2,
    const float* __restrict__ nrm, const unsigned* __restrict__ gmaxbits,
    int* __restrict__ hardcnt, int* __restrict__ hardlist, float* __restrict__ out) {
    const int i = (blockIdx.x << 2) + (threadIdx.x >> 6);   // one 64-lane wave per row
    const int lane = threadIdx.x & 63;
    const bool valid = lane < NCAND;

    int   cj  = valid ? cidx[lane] : 0;
    float cT  = valid ? ct1[lane] : -1.f;
    float cX1 = valid ? cx1[lane] : 0.f;
    float cX2 = valid ? cx2[lane] : 0.f;
    int ad = valid ? adj[(ll)i * N + cj] : 0;
    unsigned long long m = __ballot(ad > 0);

    float w1i = w1[i], w2i = w2[i];
    bool hard = false;
    int j1 = -1;
    if (m == 0ull) {
        hard = true;   // no adjacent candidate (incl. all-zero adj row) -> exact fallback
    } else {
        int f = __ffsll(m) - 1;
        j1 = __shfl(cj, f, 64);
        float t1f = __shfl(cT, f, 64);
        float x1f = __shfl(cX1, f, 64);
        float x2f = __shfl(cX2, f, 64);
        float lastT = __shfl(cT, NCAND - 1, 64);
        // tie on t1 bits among adjacent candidates -> reference may average -> fallback;
        // tie with the candidate-list boundary value -> off-list tie possible -> fallback
        unsigned long long tm = __ballot(ad > 0 && (cT == t1f));
        if (__popcll(tm) > 1 || t1f == lastT) hard = true;
        float Lx1 = w1i * x1f + w2i * x2f;
        unsigned long long m2 = m & ~(1ull << f);
        float Lx2 = -INFINITY;
        if (m2 != 0ull) {
            int s2 = __ffsll(m2) - 1;
            Lx2 = w1i * __shfl(cX1, s2, 64) + w2i * __shfl(cX2, s2, 64);
        }
        float ub  = w1i * ubx[0] + w2i * ubx[1];   // bound for ALL non-candidate columns
        float alt = fmaxf(Lx2, ub);
        float gmax = __uint_as_float(*gmaxbits);
        // |a*G| <= a*|Wh_i|*|Wh_j| both sides; + slack for f32 rounding & our-vs-ref exp diffs
        float margin = 2.0f * params[0] * nrm[i] * gmax + 100.0f + 1e-5f * Lx1;
        if (!(Lx1 - alt > margin)) hard = true;    // NaN-safe: NaN -> hard
    }
    if (hard) {
        if (lane == 0) { int p = atomicAdd(hardcnt, 1); hardlist[p] = i; }
        return;
    }
    // easy: softmax is exactly one-hot at j1 -> out = ELU(Wh[j1])
    float4 v = ((const float4*)&Wh[(ll)j1 * FOUT])[lane];
    v.x = v.x > 0.f ? v.x : expm1f(v.x);
    v.y = v.y > 0.f ? v.y : expm1f(v.y);
    v.z = v.z > 0.f ? v.z : expm1f(v.z);
    v.w = v.w > 0.f ? v.w : expm1f(v.w);
    ((float4*)&out[(ll)i * FOUT])[lane] = v;
}

// ---------------- kernel 5a: hard rows — logits + row max (parallel over chunks) ----------------
__global__ __launch_bounds__(256) void hardA_kernel(
    const float* __restrict__ Wh, const float* __restrict__ params,
    const int* __restrict__ adj, const float* __restrict__ x1, const float* __restrict__ x2,
    const float* __restrict__ w1, const float* __restrict__ w2,
    const int* __restrict__ hardcnt, const int* __restrict__ hardlist,
    float* __restrict__ ebuf, unsigned* __restrict__ rowmaxenc) {
    const int h = blockIdx.x >> 5;          // 32 chunks of 256 columns
    const int chunk = blockIdx.x & 31;
    const int nh = min(*hardcnt, HMAX);
    if (h >= nh) return;
    const int i = hardlist[h];
    __shared__ float Whi[FOUT];
    __shared__ float red[4];
    const int t = threadIdx.x;
    Whi[t] = Wh[(ll)i * FOUT + t];
    __syncthreads();
    const int j = (chunk << 8) + t;
    const float4* wi4 = (const float4*)Whi;
    const float4* wr  = (const float4*)&Wh[(ll)j * FOUT];
    float s = 0.f;
#pragma unroll 8
    for (int f = 0; f < 64; ++f) {
        float4 a = wi4[f], b = wr[f];
        s = fmaf(a.x, b.x, fmaf(a.y, b.y, fmaf(a.z, b.z, fmaf(a.w, b.w, s))));
    }
    // EXACT same logit assembly as the verified R2 kernel
    float ev = fmaf(params[0], s, params[1]);
    ev = fmaf(w1[i], x1[j], ev);
    ev = fmaf(w2[i], x2[j], ev);
    ev = (adj[(ll)i * N + j] > 0) ? ev : NEGV;
    ebuf[h * N + j] = ev;
    float mx = ev;
#pragma unroll
    for (int off = 1; off < 64; off <<= 1) mx = fmaxf(mx, __shfl_xor(mx, off, 64));
    if ((t & 63) == 0) red[t >> 6] = mx;
    __syncthreads();
    if (t == 0) {
        mx = fmaxf(fmaxf(red[0], red[1]), fmaxf(red[2], red[3]));
        unsigned u = __float_as_uint(mx);
        unsigned enc = (u & 0x80000000u) ? ~u : (u | 0x80000000u);
        atomicMax(&rowmaxenc[h], enc);
    }
}

// ---------------- kernel 5b: hard rows — exp/sum + partial PV ----------------
__global__ __launch_bounds__(256) void hardB_kernel(
    const float* __restrict__ Wh, const int* __restrict__ hardcnt,
    const float* __restrict__ ebuf, const unsigned* __restrict__ rowmaxenc,
    float* __restrict__ rowsum, float* __restrict__ acc) {
    const int h = blockIdx.x >> 5;
    const int chunk = blockIdx.x & 31;
    const int nh = min(*hardcnt, HMAX);
    if (h >= nh) return;
    const int t = threadIdx.x;
    unsigned enc = rowmaxenc[h];
    unsigned u = (enc & 0x80000000u) ? (enc & 0x7fffffffu) : ~enc;
    const float mx = __uint_as_float(u);
    const int j = (chunk << 8) + t;
    float p = expf(ebuf[h * N + j] - mx);
    __shared__ float pl[256];
    pl[t] = p;
    float ps = p;
#pragma unroll
    for (int off = 1; off < 64; off <<= 1) ps += __shfl_xor(ps, off, 64);
    if ((t & 63) == 0) atomicAdd(&rowsum[h], ps);
    __syncthreads();
    float o = 0.f;
    const float* base = &Wh[(ll)(chunk << 8) * FOUT + t];
#pragma unroll 4
    for (int jj = 0; jj < 256; ++jj) o = fmaf(pl[jj], base[(ll)jj * FOUT], o);
    atomicAdd(&acc[h * FOUT + t], o);
}

// ---------------- kernel 5c: hard rows — normalize + ELU + store ----------------
__global__ __launch_bounds__(256) void hardC_kernel(
    const int* __restrict__ hardcnt, const int* __restrict__ hardlist,
    const float* __restrict__ rowsum, const float* __restrict__ acc,
    float* __restrict__ out) {
    const int h = blockIdx.x;
    const int nh = min(*hardcnt, HMAX);
    if (h >= nh) return;
    const int i = hardlist[h];
    const int t = threadIdx.x;
    float o = acc[h * FOUT + t] / rowsum[h];
    out[(ll)i * FOUT + t] = o > 0.f ? o : expm1f(o);
}

// ---------------- kernel 5d: serial overflow fallback (h >= HMAX; normally no-op) ----------------
__global__ __launch_bounds__(256) void hardtail_kernel(
    const float* __restrict__ Wh, const float* __restrict__ params,
    const int* __restrict__ adj, const float* __restrict__ x1, const float* __restrict__ x2,
    const float* __restrict__ w1, const float* __restrict__ w2,
    const int* __restrict__ hardcnt, const int* __restrict__ hardlist,
    float* __restrict__ out) {
    __shared__ float Whi[FOUT];
    __shared__ float ebuf[N];
    __shared__ float red[16];
    const int t = threadIdx.x;
    const int nh = *hardcnt;
    for (int h = HMAX + blockIdx.x; h < nh; h += gridDim.x) {
        const int i = hardlist[h];
        __syncthreads();
        Whi[t] = Wh[(ll)i * FOUT + t];
        __syncthreads();
        const float aC = params[0], cA = params[1], w1i = w1[i], w2i = w2[i];
        const float4* wi4 = (const float4*)Whi;
        for (int j0 = 0; j0 < N; j0 += 256) {
            int j = j0 + t;
            const float4* wr = (const float4*)&Wh[(ll)j * FOUT];
            float s = 0.f;
#pragma unroll 8
            for (int f = 0; f < 64; ++f) {
                float4 a = wi4[f], b = wr[f];
                s = fmaf(a.x, b.x, fmaf(a.y, b.y, fmaf(a.z, b.z, fmaf(a.w, b.w, s))));
            }
            float ev = fmaf(aC, s, cA);
            ev = fmaf(w1i, x1[j], ev);
            ev = fmaf(w2i, x2[j], ev);
            ebuf[j] = (adj[(ll)i * N + j] > 0) ? ev : NEGV;
        }
        __syncthreads();
        float mx = -INFINITY;
        for (int j = t; j < N; j += 256) mx = fmaxf(mx, ebuf[j]);
#pragma unroll
        for (int off = 1; off < 64; off <<= 1) mx = fmaxf(mx, __shfl_xor(mx, off, 64));
        if ((t & 63) == 0) red[t >> 6] = mx;
        __syncthreads();
        mx = fmaxf(fmaxf(red[0], red[1]), fmaxf(red[2], red[3]));
        float ls = 0.f;
        for (int j = t; j < N; j += 256) {
            float p = expf(ebuf[j] - mx);
            ebuf[j] = p;
            ls += p;
        }
#pragma unroll
        for (int off = 1; off < 64; off <<= 1) ls += __shfl_xor(ls, off, 64);
        if ((t & 63) == 0) red[8 + (t >> 6)] = ls;
        __syncthreads();
        ls = (red[8] + red[9]) + (red[10] + red[11]);
        float o0 = 0.f, o1 = 0.f, o2 = 0.f, o3 = 0.f;
        for (int j = 0; j < N; j += 4) {
            o0 = fmaf(ebuf[j + 0], Wh[(ll)(j + 0) * FOUT + t], o0);
            o1 = fmaf(ebuf[j + 1], Wh[(ll)(j + 1) * FOUT + t], o1);
            o2 = fmaf(ebuf[j + 2], Wh[(ll)(j + 2) * FOUT + t], o2);
            o3 = fmaf(ebuf[j + 3], Wh[(ll)(j + 3) * FOUT + t], o3);
        }
        float o = ((o0 + o1) + (o2 + o3)) / ls;
        out[(ll)i * FOUT + t] = o > 0.f ? o : expm1f(o);
    }
}

// ---------------- launch ----------------
extern "C" void kernel_launch(void* const* d_in, const int* in_sizes, int n_in,
                              void* d_out, int out_size, void* d_ws, size_t ws_size,
                              hipStream_t stream) {
    const float* h   = (const float*)d_in[0];
    const float* W   = (const float*)d_in[1];
    const float* Mui = (const float*)d_in[2];
    const int*   adj = (const int*)d_in[3];
    float* out = (float*)d_out;

    float* ws = (float*)d_ws;
    float* Wh     = ws;                         // 8192*256
    float* t1a    = Wh + N * FOUT;              // N
    float* x1     = t1a + N;
    float* x2     = x1 + N;
    float* w1     = x2 + N;
    float* w2     = w1 + N;
    float* nrm    = w2 + N;
    float* params = nrm + N;                    // 8
    float* ct1    = params + 8;                 // NCAND
    float* cx1    = ct1 + NCAND;
    float* cx2    = cx1 + NCAND;
    float* ubx    = cx2 + NCAND;                // 2
    float* o1v    = ubx + 2;                    // 1024
    float* ebuf   = o1v + 1024;                 // HMAX*N
    float* acc    = ebuf + HMAX * N;            // HMAX*FOUT
    float* rowsum = acc + HMAX * FOUT;          // HMAX
    int*   o1i       = (int*)(rowsum + HMAX);   // 1024
    int*   cidx      = o1i + 1024;              // NCAND
    int*   hardcnt   = cidx + NCAND;            // 1
    unsigned* gmaxb  = (unsigned*)(hardcnt + 1);// 1
    unsigned* rowmaxenc = gmaxb + 1;            // HMAX
    int*   hardlist  = (int*)(rowmaxenc + HMAX);// N

    wh_gemm<<<dim3(FOUT / 64, N / 64), 256, 0, stream>>>(h, W, Wh, gmaxb);
    factors2_kernel<<<N, 64, 0, stream>>>(Wh, Mui, params, t1a, x1, x2, w1, w2, nrm, gmaxb);
    topk1_kernel<<<64, 64, 0, stream>>>(t1a, o1v, o1i);
    topk2_kernel<<<1, 1024, 0, stream>>>(o1v, o1i, t1a, x1, x2,
                                         cidx, ct1, cx1, cx2, ubx, hardcnt,
                                         acc, rowsum, rowmaxenc);
    classify_kernel<<<N / 4, 256, 0, stream>>>(Wh, params, adj, cidx, ct1, cx1, cx2, ubx,
                                               w1, w2, nrm, gmaxb, hardcnt, hardlist, out);
    hardA_kernel<<<32 * HMAX, 256, 0, stream>>>(Wh, params, adj, x1, x2, w1, w2,
                                                hardcnt, hardlist, ebuf, rowmaxenc);
    hardB_kernel<<<32 * HMAX, 256, 0, stream>>>(Wh, hardcnt, ebuf, rowmaxenc, rowsum, acc);
    hardC_kernel<<<HMAX, 256, 0, stream>>>(hardcnt, hardlist, rowsum, acc, out);
    hardtail_kernel<<<128, 256, 0, stream>>>(Wh, params, adj, x1, x2, w1, w2,
                                             hardcnt, hardlist, out);
    (void)n_in; (void)in_sizes; (void)out_size; (void)ws_size;
}

// Round 9
// 419.548 us; speedup vs baseline: 1.3694x; 1.2132x over previous
//
#include <hip/hip_runtime.h>
#include <math.h>

#define N 8192
#define FIN 512
#define FOUT 256
#define NEGV (-9e15f)
#define NCAND 16
#define HMAX 16

typedef long long ll;

// ---------------- kernel 1: Wh = h @ W (8192x512x256 f32), double-buffered ----------------
__global__ __launch_bounds__(256) void wh_gemm(const float* __restrict__ A,
                                               const float* __restrict__ B,
                                               float* __restrict__ C,
                                               unsigned* __restrict__ gmaxbits) {
    __shared__ float As[32][68];
    __shared__ float Bs[32][68];
    const int tid = threadIdx.x;
    if (blockIdx.x == 0 && blockIdx.y == 0 && tid == 0) *gmaxbits = 0u;
    const int m0 = blockIdx.y * 64, n0 = blockIdx.x * 64;
    const int tx = tid & 15, ty = tid >> 4;
    const int arow = tid >> 2, ak = (tid & 3) * 8;   // A: 64 rows x 32 k
    const int brow = tid >> 3, bn = (tid & 7) * 8;   // B: 32 k x 64 n
    const float* aptr = &A[(m0 + arow) * FIN + ak];
    const float* bptr = &B[brow * FOUT + n0 + bn];
    float4 av0 = *(const float4*)aptr, av1 = *(const float4*)(aptr + 4);
    float4 bv0 = *(const float4*)bptr, bv1 = *(const float4*)(bptr + 4);
    float acc[4][4] = {};
    for (int k0 = 0; k0 < FIN; k0 += 32) {
        As[ak + 0][arow] = av0.x; As[ak + 1][arow] = av0.y;
        As[ak + 2][arow] = av0.z; As[ak + 3][arow] = av0.w;
        As[ak + 4][arow] = av1.x; As[ak + 5][arow] = av1.y;
        As[ak + 6][arow] = av1.z; As[ak + 7][arow] = av1.w;
        *(float4*)&Bs[brow][bn] = bv0;
        *(float4*)&Bs[brow][bn + 4] = bv1;
        __syncthreads();
        if (k0 + 32 < FIN) {   // prefetch next tile while this one computes
            aptr += 32; bptr += 32 * FOUT;
            av0 = *(const float4*)aptr; av1 = *(const float4*)(aptr + 4);
            bv0 = *(const float4*)bptr; bv1 = *(const float4*)(bptr + 4);
        }
#pragma unroll
        for (int k = 0; k < 32; ++k) {
            float4 a = *(const float4*)&As[k][4 * ty];
            float4 b = *(const float4*)&Bs[k][4 * tx];
            float ar[4] = {a.x, a.y, a.z, a.w};
            float br[4] = {b.x, b.y, b.z, b.w};
#pragma unroll
            for (int i = 0; i < 4; ++i)
#pragma unroll
                for (int j = 0; j < 4; ++j)
                    acc[i][j] = fmaf(ar[i], br[j], acc[i][j]);
        }
        __syncthreads();
    }
#pragma unroll
    for (int i = 0; i < 4; ++i) {
        float4 v = make_float4(acc[i][0], acc[i][1], acc[i][2], acc[i][3]);
        *(float4*)&C[(m0 + 4 * ty + i) * FOUT + n0 + 4 * tx] = v;
    }
}

// ---------------- kernel 2: per-row factors + t1 + norms (NO global atomics) ----------------
// 256 threads = 4 waves = 4 rows per block; block 0 publishes params.
__global__ __launch_bounds__(256) void factors2_kernel(
    const float* __restrict__ Wh, const float* __restrict__ Mui,
    float* __restrict__ params,
    float* __restrict__ t1a, float* __restrict__ x1, float* __restrict__ x2,
    float* __restrict__ w1, float* __restrict__ w2,
    float* __restrict__ nrm) {
    const int t = threadIdx.x;
    const int lane = t & 63;
    const int i = blockIdx.x * 4 + (t >> 6);
    float4 v = ((const float4*)&Wh[(ll)i * FOUT])[lane];
    float s = v.x * v.x + v.y * v.y + v.z * v.z + v.w * v.w;
#pragma unroll
    for (int off = 1; off < 64; off <<= 1) s += __shfl_xor(s, off, 64);
    if (lane == 0) {
        // recompute mui softmax in-register (identical expressions to verified R2 path)
        float m = Mui[0];
        for (int q = 1; q < 6; ++q) m = fmaxf(m, Mui[q]);
        float e[6], es = 0.f;
        for (int q = 0; q < 6; ++q) { e[q] = expf(Mui[q] - m); es += e[q]; }
        float mui[6];
        for (int q = 0; q < 6; ++q) mui[q] = e[q] / es;
        float p2 = 256.0f * mui[4], p3 = 256.0f * mui[5];
        if (i == 0) {
            params[0] = mui[0] + mui[1] + mui[2] + mui[3];
            params[1] = 0.5f * (mui[0] + mui[1]) + 1.0f * (mui[2] + mui[3]);
            params[2] = p2;
            params[3] = p3;
        }
        nrm[i] = sqrtf(s);
        float tt = Wh[(ll)i * FOUT + 1];
        float t1 = tt * tt;                          // exact same expr as verified R2 kernel
        t1a[i] = t1;
        x1[i] = expf(0.5f * t1);
        x2[i] = expf(t1);
        w1[i] = p2 * expf(-0.5f * t1);
        w2[i] = p3 * expf(-t1);
    }
}

// ---------------- kernel 2b: two-level max over nrm -> gmaxbits (8 atomics total) ----------------
__global__ __launch_bounds__(256) void nrmmax_kernel(const float* __restrict__ nrm,
                                                     unsigned* __restrict__ gmaxbits) {
    __shared__ float red[4];
    const int t = threadIdx.x;
    float4 v = ((const float4*)nrm)[blockIdx.x * 256 + t];   // 8 blocks x 256 x 4 = 8192
    float m = fmaxf(fmaxf(v.x, v.y), fmaxf(v.z, v.w));
#pragma unroll
    for (int off = 1; off < 64; off <<= 1) m = fmaxf(m, __shfl_xor(m, off, 64));
    if ((t & 63) == 0) red[t >> 6] = m;
    __syncthreads();
    if (t == 0) {
        m = fmaxf(fmaxf(red[0], red[1]), fmaxf(red[2], red[3]));
        atomicMax(gmaxbits, __float_as_uint(m));   // nrm > 0 -> bit-monotone
    }
}

// ---------------- kernel 3a: per-slice top-16 (64 blocks x 128 rows, 1 wave) ----------------
__global__ __launch_bounds__(64) void topk1_kernel(const float* __restrict__ t1a,
                                                   float* __restrict__ o1v,
                                                   int* __restrict__ o1i) {
    const int l = threadIdx.x;
    const int base = blockIdx.x * 128;
    float v0 = t1a[base + l], v1 = t1a[base + 64 + l];
    int i0 = base + l, i1 = base + 64 + l;
    for (int r = 0; r < NCAND; ++r) {
        float mv; int mi;
        if (v0 >= v1) { mv = v0; mi = i0; } else { mv = v1; mi = i1; }
#pragma unroll
        for (int off = 1; off < 64; off <<= 1) {
            float ov = __shfl_xor(mv, off, 64);
            int   oi = __shfl_xor(mi, off, 64);
            if (ov > mv || (ov == mv && oi < mi)) { mv = ov; mi = oi; }
        }
        if (mi == i0) v0 = -2.f;
        if (mi == i1) v1 = -2.f;
        if (l == r) { o1v[blockIdx.x * NCAND + r] = mv; o1i[blockIdx.x * NCAND + r] = mi; }
    }
}

// ---------------- kernel 3b: global top-16 + init hard accumulators (1 block) ----------------
__global__ __launch_bounds__(1024) void topk2_kernel(
    const float* __restrict__ o1v, const int* __restrict__ o1i,
    const float* __restrict__ t1a, const float* __restrict__ x1, const float* __restrict__ x2,
    int* __restrict__ cidx, float* __restrict__ ct1, float* __restrict__ cx1,
    float* __restrict__ cx2, float* __restrict__ ubx, int* __restrict__ hardcnt,
    float* __restrict__ acc, float* __restrict__ rowsum, unsigned* __restrict__ rowmaxenc) {
    __shared__ float lv[16];
    __shared__ int li[16];
    __shared__ float bvs;
    __shared__ int bis;
    const int t = threadIdx.x;
#pragma unroll
    for (int q = 0; q < HMAX * FOUT / 1024; ++q) acc[q * 1024 + t] = 0.f;
    if (t < HMAX) { rowsum[t] = 0.f; rowmaxenc[t] = 0u; }
    float v = o1v[t];
    int idx = o1i[t];
    for (int r = 0; r < NCAND; ++r) {
        float mv = v; int mi = idx;
#pragma unroll
        for (int off = 1; off < 64; off <<= 1) {
            float ov = __shfl_xor(mv, off, 64);
            int   oi = __shfl_xor(mi, off, 64);
            if (ov > mv || (ov == mv && oi < mi)) { mv = ov; mi = oi; }
        }
        if ((t & 63) == 0) { lv[t >> 6] = mv; li[t >> 6] = mi; }
        __syncthreads();
        if (t < 64) {
            float m2 = (t < 16) ? lv[t] : -3.f;
            int   i2 = (t < 16) ? li[t] : -1;
#pragma unroll
            for (int off = 1; off < 16; off <<= 1) {
                float ov = __shfl_xor(m2, off, 64);
                int   oi = __shfl_xor(i2, off, 64);
                if (ov > m2 || (ov == m2 && oi < i2)) { m2 = ov; i2 = oi; }
            }
            if (t == 0) { bvs = m2; bis = i2; }
        }
        __syncthreads();
        if (idx == bis) v = -2.f;
        if (t == r) cidx[r] = bis;
    }
    __syncthreads();
    if (t < NCAND) {
        int j = cidx[t];
        ct1[t] = t1a[j];
        cx1[t] = x1[j];
        cx2[t] = x2[j];
    }
    if (t == 0) {
        int j = cidx[NCAND - 1];
        ubx[0] = x1[j];
        ubx[1] = x2[j];
        *hardcnt = 0;
    }
}

// ---------------- kernel 4: classify rows; write easy rows (one wave per row) ----------------
__global__ __launch_bounds__(256) void classify_kernel(
    const float* __restrict__ Wh, const float* __restrict__ params,
    const int* __restrict__ adj, const int* __restrict__ cidx,
    const float* __restrict__ ct1, const float* __restrict__ cx1, const float* __restrict__ cx2,
    const float* __restrict__ ubx, const float* __restrict__ w1, const float* __restrict__ w2,
    const float* __restrict__ nrm, const unsigned* __restrict__ gmaxbits,
    int* __restrict__ hardcnt, int* __restrict__ hardlist, float* __restrict__ out) {
    const int i = (blockIdx.x << 2) + (threadIdx.x >> 6);   // one 64-lane wave per row
    const int lane = threadIdx.x & 63;
    const bool valid = lane < NCAND;

    int   cj  = valid ? cidx[lane] : 0;
    float cT  = valid ? ct1[lane] : -1.f;
    float cX1 = valid ? cx1[lane] : 0.f;
    float cX2 = valid ? cx2[lane] : 0.f;
    int ad = valid ? adj[(ll)i * N + cj] : 0;
    unsigned long long m = __ballot(ad > 0);

    float w1i = w1[i], w2i = w2[i];
    bool hard = false;
    int j1 = -1;
    if (m == 0ull) {
        hard = true;   // no adjacent candidate (incl. all-zero adj row) -> exact fallback
    } else {
        int f = __ffsll(m) - 1;
        j1 = __shfl(cj, f, 64);
        float t1f = __shfl(cT, f, 64);
        float x1f = __shfl(cX1, f, 64);
        float x2f = __shfl(cX2, f, 64);
        float lastT = __shfl(cT, NCAND - 1, 64);
        unsigned long long tm = __ballot(ad > 0 && (cT == t1f));
        if (__popcll(tm) > 1 || t1f == lastT) hard = true;
        float Lx1 = w1i * x1f + w2i * x2f;
        unsigned long long m2 = m & ~(1ull << f);
        float Lx2 = -INFINITY;
        if (m2 != 0ull) {
            int s2 = __ffsll(m2) - 1;
            Lx2 = w1i * __shfl(cX1, s2, 64) + w2i * __shfl(cX2, s2, 64);
        }
        float ub  = w1i * ubx[0] + w2i * ubx[1];   // bound for ALL non-candidate columns
        float alt = fmaxf(Lx2, ub);
        float gmax = __uint_as_float(*gmaxbits);
        float margin = 2.0f * params[0] * nrm[i] * gmax + 100.0f + 1e-5f * Lx1;
        if (!(Lx1 - alt > margin)) hard = true;    // NaN-safe: NaN -> hard
    }
    if (hard) {
        if (lane == 0) { int p = atomicAdd(hardcnt, 1); hardlist[p] = i; }
        return;
    }
    float4 v = ((const float4*)&Wh[(ll)j1 * FOUT])[lane];
    v.x = v.x > 0.f ? v.x : expm1f(v.x);
    v.y = v.y > 0.f ? v.y : expm1f(v.y);
    v.z = v.z > 0.f ? v.z : expm1f(v.z);
    v.w = v.w > 0.f ? v.w : expm1f(v.w);
    ((float4*)&out[(ll)i * FOUT])[lane] = v;
}

// ---------------- kernel 5a: hard rows — logits + row max (parallel over chunks) ----------------
__global__ __launch_bounds__(256) void hardA_kernel(
    const float* __restrict__ Wh, const float* __restrict__ params,
    const int* __restrict__ adj, const float* __restrict__ x1, const float* __restrict__ x2,
    const float* __restrict__ w1, const float* __restrict__ w2,
    const int* __restrict__ hardcnt, const int* __restrict__ hardlist,
    float* __restrict__ ebuf, unsigned* __restrict__ rowmaxenc) {
    const int h = blockIdx.x >> 5;          // 32 chunks of 256 columns
    const int chunk = blockIdx.x & 31;
    const int nh = min(*hardcnt, HMAX);
    if (h >= nh) return;
    const int i = hardlist[h];
    __shared__ float Whi[FOUT];
    __shared__ float red[4];
    const int t = threadIdx.x;
    Whi[t] = Wh[(ll)i * FOUT + t];
    __syncthreads();
    const int j = (chunk << 8) + t;
    const float4* wi4 = (const float4*)Whi;
    const float4* wr  = (const float4*)&Wh[(ll)j * FOUT];
    float s = 0.f;
#pragma unroll 8
    for (int f = 0; f < 64; ++f) {
        float4 a = wi4[f], b = wr[f];
        s = fmaf(a.x, b.x, fmaf(a.y, b.y, fmaf(a.z, b.z, fmaf(a.w, b.w, s))));
    }
    float ev = fmaf(params[0], s, params[1]);
    ev = fmaf(w1[i], x1[j], ev);
    ev = fmaf(w2[i], x2[j], ev);
    ev = (adj[(ll)i * N + j] > 0) ? ev : NEGV;
    ebuf[h * N + j] = ev;
    float mx = ev;
#pragma unroll
    for (int off = 1; off < 64; off <<= 1) mx = fmaxf(mx, __shfl_xor(mx, off, 64));
    if ((t & 63) == 0) red[t >> 6] = mx;
    __syncthreads();
    if (t == 0) {
        mx = fmaxf(fmaxf(red[0], red[1]), fmaxf(red[2], red[3]));
        unsigned u = __float_as_uint(mx);
        unsigned enc = (u & 0x80000000u) ? ~u : (u | 0x80000000u);
        atomicMax(&rowmaxenc[h], enc);
    }
}

// ---------------- kernel 5b: hard rows — exp/sum + partial PV ----------------
__global__ __launch_bounds__(256) void hardB_kernel(
    const float* __restrict__ Wh, const int* __restrict__ hardcnt,
    const float* __restrict__ ebuf, const unsigned* __restrict__ rowmaxenc,
    float* __restrict__ rowsum, float* __restrict__ acc) {
    const int h = blockIdx.x >> 5;
    const int chunk = blockIdx.x & 31;
    const int nh = min(*hardcnt, HMAX);
    if (h >= nh) return;
    const int t = threadIdx.x;
    unsigned enc = rowmaxenc[h];
    unsigned u = (enc & 0x80000000u) ? (enc & 0x7fffffffu) : ~enc;
    const float mx = __uint_as_float(u);
    const int j = (chunk << 8) + t;
    float p = expf(ebuf[h * N + j] - mx);
    __shared__ float pl[256];
    pl[t] = p;
    float ps = p;
#pragma unroll
    for (int off = 1; off < 64; off <<= 1) ps += __shfl_xor(ps, off, 64);
    if ((t & 63) == 0) atomicAdd(&rowsum[h], ps);
    __syncthreads();
    float o = 0.f;
    const float* base = &Wh[(ll)(chunk << 8) * FOUT + t];
#pragma unroll 4
    for (int jj = 0; jj < 256; ++jj) o = fmaf(pl[jj], base[(ll)jj * FOUT], o);
    atomicAdd(&acc[h * FOUT + t], o);
}

// ---------------- kernel 5c: hard rows — normalize + ELU + store ----------------
__global__ __launch_bounds__(256) void hardC_kernel(
    const int* __restrict__ hardcnt, const int* __restrict__ hardlist,
    const float* __restrict__ rowsum, const float* __restrict__ acc,
    float* __restrict__ out) {
    const int h = blockIdx.x;
    const int nh = min(*hardcnt, HMAX);
    if (h >= nh) return;
    const int i = hardlist[h];
    const int t = threadIdx.x;
    float o = acc[h * FOUT + t] / rowsum[h];
    out[(ll)i * FOUT + t] = o > 0.f ? o : expm1f(o);
}

// ---------------- kernel 5d: serial overflow fallback (h >= HMAX; normally no-op) ----------------
__global__ __launch_bounds__(256) void hardtail_kernel(
    const float* __restrict__ Wh, const float* __restrict__ params,
    const int* __restrict__ adj, const float* __restrict__ x1, const float* __restrict__ x2,
    const float* __restrict__ w1, const float* __restrict__ w2,
    const int* __restrict__ hardcnt, const int* __restrict__ hardlist,
    float* __restrict__ out) {
    __shared__ float Whi[FOUT];
    __shared__ float ebuf[N];
    __shared__ float red[16];
    const int t = threadIdx.x;
    const int nh = *hardcnt;
    for (int h = HMAX + blockIdx.x; h < nh; h += gridDim.x) {
        const int i = hardlist[h];
        __syncthreads();
        Whi[t] = Wh[(ll)i * FOUT + t];
        __syncthreads();
        const float aC = params[0], cA = params[1], w1i = w1[i], w2i = w2[i];
        const float4* wi4 = (const float4*)Whi;
        for (int j0 = 0; j0 < N; j0 += 256) {
            int j = j0 + t;
            const float4* wr = (const float4*)&Wh[(ll)j * FOUT];
            float s = 0.f;
#pragma unroll 8
            for (int f = 0; f < 64; ++f) {
                float4 a = wi4[f], b = wr[f];
                s = fmaf(a.x, b.x, fmaf(a.y, b.y, fmaf(a.z, b.z, fmaf(a.w, b.w, s))));
            }
            float ev = fmaf(aC, s, cA);
            ev = fmaf(w1i, x1[j], ev);
            ev = fmaf(w2i, x2[j], ev);
            ebuf[j] = (adj[(ll)i * N + j] > 0) ? ev : NEGV;
        }
        __syncthreads();
        float mx = -INFINITY;
        for (int j = t; j < N; j += 256) mx = fmaxf(mx, ebuf[j]);
#pragma unroll
        for (int off = 1; off < 64; off <<= 1) mx = fmaxf(mx, __shfl_xor(mx, off, 64));
        if ((t & 63) == 0) red[t >> 6] = mx;
        __syncthreads();
        mx = fmaxf(fmaxf(red[0], red[1]), fmaxf(red[2], red[3]));
        float ls = 0.f;
        for (int j = t; j < N; j += 256) {
            float p = expf(ebuf[j] - mx);
            ebuf[j] = p;
            ls += p;
        }
#pragma unroll
        for (int off = 1; off < 64; off <<= 1) ls += __shfl_xor(ls, off, 64);
        if ((t & 63) == 0) red[8 + (t >> 6)] = ls;
        __syncthreads();
        ls = (red[8] + red[9]) + (red[10] + red[11]);
        float o0 = 0.f, o1 = 0.f, o2 = 0.f, o3 = 0.f;
        for (int j = 0; j < N; j += 4) {
            o0 = fmaf(ebuf[j + 0], Wh[(ll)(j + 0) * FOUT + t], o0);
            o1 = fmaf(ebuf[j + 1], Wh[(ll)(j + 1) * FOUT + t], o1);
            o2 = fmaf(ebuf[j + 2], Wh[(ll)(j + 2) * FOUT + t], o2);
            o3 = fmaf(ebuf[j + 3], Wh[(ll)(j + 3) * FOUT + t], o3);
        }
        float o = ((o0 + o1) + (o2 + o3)) / ls;
        out[(ll)i * FOUT + t] = o > 0.f ? o : expm1f(o);
    }
}

// ---------------- launch ----------------
extern "C" void kernel_launch(void* const* d_in, const int* in_sizes, int n_in,
                              void* d_out, int out_size, void* d_ws, size_t ws_size,
                              hipStream_t stream) {
    const float* h   = (const float*)d_in[0];
    const float* W   = (const float*)d_in[1];
    const float* Mui = (const float*)d_in[2];
    const int*   adj = (const int*)d_in[3];
    float* out = (float*)d_out;

    float* ws = (float*)d_ws;
    float* Wh     = ws;                         // 8192*256
    float* t1a    = Wh + N * FOUT;              // N
    float* x1     = t1a + N;
    float* x2     = x1 + N;
    float* w1     = x2 + N;
    float* w2     = w1 + N;
    float* nrm    = w2 + N;
    float* params = nrm + N;                    // 8
    float* ct1    = params + 8;                 // NCAND
    float* cx1    = ct1 + NCAND;
    float* cx2    = cx1 + NCAND;
    float* ubx    = cx2 + NCAND;                // 2
    float* o1v    = ubx + 2;                    // 1024
    float* ebuf   = o1v + 1024;                 // HMAX*N
    float* acc    = ebuf + HMAX * N;            // HMAX*FOUT
    float* rowsum = acc + HMAX * FOUT;          // HMAX
    int*   o1i       = (int*)(rowsum + HMAX);   // 1024
    int*   cidx      = o1i + 1024;              // NCAND
    int*   hardcnt   = cidx + NCAND;            // 1
    unsigned* gmaxb  = (unsigned*)(hardcnt + 1);// 1
    unsigned* rowmaxenc = gmaxb + 1;            // HMAX
    int*   hardlist  = (int*)(rowmaxenc + HMAX);// N

    wh_gemm<<<dim3(FOUT / 64, N / 64), 256, 0, stream>>>(h, W, Wh, gmaxb);
    factors2_kernel<<<N / 4, 256, 0, stream>>>(Wh, Mui, params, t1a, x1, x2, w1, w2, nrm);
    nrmmax_kernel<<<8, 256, 0, stream>>>(nrm, gmaxb);
    topk1_kernel<<<64, 64, 0, stream>>>(t1a, o1v, o1i);
    topk2_kernel<<<1, 1024, 0, stream>>>(o1v, o1i, t1a, x1, x2,
                                         cidx, ct1, cx1, cx2, ubx, hardcnt,
                                         acc, rowsum, rowmaxenc);
    classify_kernel<<<N / 4, 256, 0, stream>>>(Wh, params, adj, cidx, ct1, cx1, cx2, ubx,
                                               w1, w2, nrm, gmaxb, hardcnt, hardlist, out);
    hardA_kernel<<<32 * HMAX, 256, 0, stream>>>(Wh, params, adj, x1, x2, w1, w2,
                                                hardcnt, hardlist, ebuf, rowmaxenc);
    hardB_kernel<<<32 * HMAX, 256, 0, stream>>>(Wh, hardcnt, ebuf, rowmaxenc, rowsum, acc);
    hardC_kernel<<<HMAX, 256, 0, stream>>>(hardcnt, hardlist, rowsum, acc, out);
    hardtail_kernel<<<128, 256, 0, stream>>>(Wh, params, adj, x1, x2, w1, w2,
                                             hardcnt, hardlist, out);
    (void)n_in; (void)in_sizes; (void)out_size; (void)ws_size;
}

// Round 10
// 416.594 us; speedup vs baseline: 1.3791x; 1.0071x over previous
//
#include <hip/hip_runtime.h>
#include <math.h>

#define N 8192
#define FIN 512
#define FOUT 256
#define NEGV (-9e15f)
#define NCAND 16
#define HMAX 16

typedef long long ll;

// ---------------- kernel 1: Wh = h @ W (8192x512x256 f32), double-buffered ----------------
__global__ __launch_bounds__(256) void wh_gemm(const float* __restrict__ A,
                                               const float* __restrict__ B,
                                               float* __restrict__ C,
                                               unsigned* __restrict__ gmaxbits) {
    __shared__ float As[32][68];
    __shared__ float Bs[32][68];
    const int tid = threadIdx.x;
    if (blockIdx.x == 0 && blockIdx.y == 0 && tid == 0) *gmaxbits = 0u;
    const int m0 = blockIdx.y * 64, n0 = blockIdx.x * 64;
    const int tx = tid & 15, ty = tid >> 4;
    const int arow = tid >> 2, ak = (tid & 3) * 8;   // A: 64 rows x 32 k
    const int brow = tid >> 3, bn = (tid & 7) * 8;   // B: 32 k x 64 n
    const float* aptr = &A[(m0 + arow) * FIN + ak];
    const float* bptr = &B[brow * FOUT + n0 + bn];
    float4 av0 = *(const float4*)aptr, av1 = *(const float4*)(aptr + 4);
    float4 bv0 = *(const float4*)bptr, bv1 = *(const float4*)(bptr + 4);
    float acc[4][4] = {};
    for (int k0 = 0; k0 < FIN; k0 += 32) {
        As[ak + 0][arow] = av0.x; As[ak + 1][arow] = av0.y;
        As[ak + 2][arow] = av0.z; As[ak + 3][arow] = av0.w;
        As[ak + 4][arow] = av1.x; As[ak + 5][arow] = av1.y;
        As[ak + 6][arow] = av1.z; As[ak + 7][arow] = av1.w;
        *(float4*)&Bs[brow][bn] = bv0;
        *(float4*)&Bs[brow][bn + 4] = bv1;
        __syncthreads();
        if (k0 + 32 < FIN) {   // prefetch next tile while this one computes
            aptr += 32; bptr += 32 * FOUT;
            av0 = *(const float4*)aptr; av1 = *(const float4*)(aptr + 4);
            bv0 = *(const float4*)bptr; bv1 = *(const float4*)(bptr + 4);
        }
#pragma unroll
        for (int k = 0; k < 32; ++k) {
            float4 a = *(const float4*)&As[k][4 * ty];
            float4 b = *(const float4*)&Bs[k][4 * tx];
            float ar[4] = {a.x, a.y, a.z, a.w};
            float br[4] = {b.x, b.y, b.z, b.w};
#pragma unroll
            for (int i = 0; i < 4; ++i)
#pragma unroll
                for (int j = 0; j < 4; ++j)
                    acc[i][j] = fmaf(ar[i], br[j], acc[i][j]);
        }
        __syncthreads();
    }
#pragma unroll
    for (int i = 0; i < 4; ++i) {
        float4 v = make_float4(acc[i][0], acc[i][1], acc[i][2], acc[i][3]);
        *(float4*)&C[(m0 + 4 * ty + i) * FOUT + n0 + 4 * tx] = v;
    }
}

// ---------------- kernel 2: per-row factors + t1 + norms (no global atomics) ----------------
__global__ __launch_bounds__(256) void factors2_kernel(
    const float* __restrict__ Wh, const float* __restrict__ Mui,
    float* __restrict__ params,
    float* __restrict__ t1a, float* __restrict__ x1, float* __restrict__ x2,
    float* __restrict__ w1, float* __restrict__ w2,
    float* __restrict__ nrm) {
    const int t = threadIdx.x;
    const int lane = t & 63;
    const int i = blockIdx.x * 4 + (t >> 6);
    float4 v = ((const float4*)&Wh[(ll)i * FOUT])[lane];
    float s = v.x * v.x + v.y * v.y + v.z * v.z + v.w * v.w;
#pragma unroll
    for (int off = 1; off < 64; off <<= 1) s += __shfl_xor(s, off, 64);
    if (lane == 0) {
        // recompute mui softmax in-register (identical expressions to verified R2 path)
        float m = Mui[0];
        for (int q = 1; q < 6; ++q) m = fmaxf(m, Mui[q]);
        float e[6], es = 0.f;
        for (int q = 0; q < 6; ++q) { e[q] = expf(Mui[q] - m); es += e[q]; }
        float mui[6];
        for (int q = 0; q < 6; ++q) mui[q] = e[q] / es;
        float p2 = 256.0f * mui[4], p3 = 256.0f * mui[5];
        if (i == 0) {
            params[0] = mui[0] + mui[1] + mui[2] + mui[3];
            params[1] = 0.5f * (mui[0] + mui[1]) + 1.0f * (mui[2] + mui[3]);
            params[2] = p2;
            params[3] = p3;
        }
        nrm[i] = sqrtf(s);
        float tt = Wh[(ll)i * FOUT + 1];
        float t1 = tt * tt;                          // exact same expr as verified R2 kernel
        t1a[i] = t1;
        x1[i] = expf(0.5f * t1);
        x2[i] = expf(t1);
        w1[i] = p2 * expf(-0.5f * t1);
        w2[i] = p3 * expf(-t1);
    }
}

// ---------------- kernel 3a: fused nrm-max + per-slice top-16 (64 blocks x 1 wave) ----------------
__global__ __launch_bounds__(64) void redtopk1_kernel(const float* __restrict__ t1a,
                                                      const float* __restrict__ nrm,
                                                      unsigned* __restrict__ gmaxbits,
                                                      float* __restrict__ o1v,
                                                      int* __restrict__ o1i) {
    const int l = threadIdx.x;
    const int base = blockIdx.x * 128;
    // nrm max over this block's 128 rows -> 64 atomics chip-wide
    float nm = fmaxf(nrm[base + l], nrm[base + 64 + l]);
#pragma unroll
    for (int off = 1; off < 64; off <<= 1) nm = fmaxf(nm, __shfl_xor(nm, off, 64));
    if (l == 0) atomicMax(gmaxbits, __float_as_uint(nm));   // nrm > 0 -> bit-monotone
    // per-slice top-16 of t1
    float v0 = t1a[base + l], v1 = t1a[base + 64 + l];
    int i0 = base + l, i1 = base + 64 + l;
    for (int r = 0; r < NCAND; ++r) {
        float mv; int mi;
        if (v0 >= v1) { mv = v0; mi = i0; } else { mv = v1; mi = i1; }
#pragma unroll
        for (int off = 1; off < 64; off <<= 1) {
            float ov = __shfl_xor(mv, off, 64);
            int   oi = __shfl_xor(mi, off, 64);
            if (ov > mv || (ov == mv && oi < mi)) { mv = ov; mi = oi; }
        }
        if (mi == i0) v0 = -2.f;
        if (mi == i1) v1 = -2.f;
        if (l == r) { o1v[blockIdx.x * NCAND + r] = mv; o1i[blockIdx.x * NCAND + r] = mi; }
    }
}

// ---------------- kernel 3b: global top-16 + hard init + celu table (1 block) ----------------
__global__ __launch_bounds__(1024) void topk2_kernel(
    const float* __restrict__ o1v, const int* __restrict__ o1i,
    const float* __restrict__ t1a, const float* __restrict__ x1, const float* __restrict__ x2,
    const float* __restrict__ Wh,
    int* __restrict__ cidx, float* __restrict__ ct1, float* __restrict__ cx1,
    float* __restrict__ cx2, float* __restrict__ ubx, int* __restrict__ hardcnt,
    float* __restrict__ acc, float* __restrict__ rowsum, unsigned* __restrict__ rowmaxenc,
    float* __restrict__ celu) {
    __shared__ float lv[16];
    __shared__ int li[16];
    __shared__ float bvs;
    __shared__ int bis;
    const int t = threadIdx.x;
#pragma unroll
    for (int q = 0; q < HMAX * FOUT / 1024; ++q) acc[q * 1024 + t] = 0.f;
    if (t < HMAX) { rowsum[t] = 0.f; rowmaxenc[t] = 0u; }
    float v = o1v[t];
    int idx = o1i[t];
    for (int r = 0; r < NCAND; ++r) {
        float mv = v; int mi = idx;
#pragma unroll
        for (int off = 1; off < 64; off <<= 1) {
            float ov = __shfl_xor(mv, off, 64);
            int   oi = __shfl_xor(mi, off, 64);
            if (ov > mv || (ov == mv && oi < mi)) { mv = ov; mi = oi; }
        }
        if ((t & 63) == 0) { lv[t >> 6] = mv; li[t >> 6] = mi; }
        __syncthreads();
        if (t < 64) {
            float m2 = (t < 16) ? lv[t] : -3.f;
            int   i2 = (t < 16) ? li[t] : -1;
#pragma unroll
            for (int off = 1; off < 16; off <<= 1) {
                float ov = __shfl_xor(m2, off, 64);
                int   oi = __shfl_xor(i2, off, 64);
                if (ov > m2 || (ov == m2 && oi < i2)) { m2 = ov; i2 = oi; }
            }
            if (t == 0) { bvs = m2; bis = i2; }
        }
        __syncthreads();
        if (idx == bis) v = -2.f;
        if (t == r) cidx[r] = bis;
    }
    __syncthreads();
    if (t < NCAND) {
        int j = cidx[t];
        ct1[t] = t1a[j];
        cx1[t] = x1[j];
        cx2[t] = x2[j];
    }
    if (t == 0) {
        int j = cidx[NCAND - 1];
        ubx[0] = x1[j];
        ubx[1] = x2[j];
        *hardcnt = 0;
    }
    // celu[q] = ELU(Wh[cidx[q]]) — 16 rows x 64 float4 = exactly 1024 threads
    {
        const int q = t >> 6, cc = (t & 63) * 4;
        const int row = cidx[q];
        float4 w = *(const float4*)&Wh[(ll)row * FOUT + cc];
        w.x = w.x > 0.f ? w.x : expm1f(w.x);
        w.y = w.y > 0.f ? w.y : expm1f(w.y);
        w.z = w.z > 0.f ? w.z : expm1f(w.z);
        w.w = w.w > 0.f ? w.w : expm1f(w.w);
        *(float4*)&celu[q * FOUT + cc] = w;
    }
}

// ---------------- kernel 4: classify rows; write easy rows (one wave per row) ----------------
__global__ __launch_bounds__(256) void classify_kernel(
    const float* __restrict__ celu, const float* __restrict__ params,
    const int* __restrict__ adj, const int* __restrict__ cidx,
    const float* __restrict__ ct1, const float* __restrict__ cx1, const float* __restrict__ cx2,
    const float* __restrict__ ubx, const float* __restrict__ w1, const float* __restrict__ w2,
    const float* __restrict__ nrm, const unsigned* __restrict__ gmaxbits,
    int* __restrict__ hardcnt, int* __restrict__ hardlist, float* __restrict__ out) {
    const int i = (blockIdx.x << 2) + (threadIdx.x >> 6);   // one 64-lane wave per row
    const int lane = threadIdx.x & 63;
    const bool valid = lane < NCAND;

    int   cj  = valid ? cidx[lane] : 0;
    float cT  = valid ? ct1[lane] : -1.f;
    float cX1 = valid ? cx1[lane] : 0.f;
    float cX2 = valid ? cx2[lane] : 0.f;
    int ad = valid ? adj[(ll)i * N + cj] : 0;
    unsigned long long m = __ballot(ad > 0);

    float w1i = w1[i], w2i = w2[i];
    bool hard = false;
    int f = -1;
    if (m == 0ull) {
        hard = true;   // no adjacent candidate (incl. all-zero adj row) -> exact fallback
    } else {
        f = __ffsll(m) - 1;
        float t1f = __shfl(cT, f, 64);
        float x1f = __shfl(cX1, f, 64);
        float x2f = __shfl(cX2, f, 64);
        float lastT = __shfl(cT, NCAND - 1, 64);
        // tie on t1 bits among adjacent candidates -> reference may average -> fallback;
        // tie with the candidate-list boundary value -> off-list tie possible -> fallback
        unsigned long long tm = __ballot(ad > 0 && (cT == t1f));
        if (__popcll(tm) > 1 || t1f == lastT) hard = true;
        float Lx1 = w1i * x1f + w2i * x2f;
        unsigned long long m2 = m & ~(1ull << f);
        float Lx2 = -INFINITY;
        if (m2 != 0ull) {
            int s2 = __ffsll(m2) - 1;
            Lx2 = w1i * __shfl(cX1, s2, 64) + w2i * __shfl(cX2, s2, 64);
        }
        float ub  = w1i * ubx[0] + w2i * ubx[1];   // bound for ALL non-candidate columns
        float alt = fmaxf(Lx2, ub);
        float gmax = __uint_as_float(*gmaxbits);
        float margin = 2.0f * params[0] * nrm[i] * gmax + 100.0f + 1e-5f * Lx1;
        if (!(Lx1 - alt > margin)) hard = true;    // NaN-safe: NaN -> hard
    }
    if (hard) {
        if (lane == 0) { int p = atomicAdd(hardcnt, 1); hardlist[p] = i; }
        return;
    }
    // easy: softmax exactly one-hot at candidate rank f -> out = celu[f] (precomputed)
    float4 v = ((const float4*)&celu[(ll)f * FOUT])[lane];
    ((float4*)&out[(ll)i * FOUT])[lane] = v;
}

// ---------------- kernel 5a: hard rows — logits + row max (parallel over chunks) ----------------
__global__ __launch_bounds__(256) void hardA_kernel(
    const float* __restrict__ Wh, const float* __restrict__ params,
    const int* __restrict__ adj, const float* __restrict__ x1, const float* __restrict__ x2,
    const float* __restrict__ w1, const float* __restrict__ w2,
    const int* __restrict__ hardcnt, const int* __restrict__ hardlist,
    float* __restrict__ ebuf, unsigned* __restrict__ rowmaxenc) {
    const int h = blockIdx.x >> 5;          // 32 chunks of 256 columns
    const int chunk = blockIdx.x & 31;
    const int nh = min(*hardcnt, HMAX);
    if (h >= nh) return;
    const int i = hardlist[h];
    __shared__ float Whi[FOUT];
    __shared__ float red[4];
    const int t = threadIdx.x;
    Whi[t] = Wh[(ll)i * FOUT + t];
    __syncthreads();
    const int j = (chunk << 8) + t;
    const float4* wi4 = (const float4*)Whi;
    const float4* wr  = (const float4*)&Wh[(ll)j * FOUT];
    float s = 0.f;
#pragma unroll 8
    for (int f = 0; f < 64; ++f) {
        float4 a = wi4[f], b = wr[f];
        s = fmaf(a.x, b.x, fmaf(a.y, b.y, fmaf(a.z, b.z, fmaf(a.w, b.w, s))));
    }
    float ev = fmaf(params[0], s, params[1]);
    ev = fmaf(w1[i], x1[j], ev);
    ev = fmaf(w2[i], x2[j], ev);
    ev = (adj[(ll)i * N + j] > 0) ? ev : NEGV;
    ebuf[h * N + j] = ev;
    float mx = ev;
#pragma unroll
    for (int off = 1; off < 64; off <<= 1) mx = fmaxf(mx, __shfl_xor(mx, off, 64));
    if ((t & 63) == 0) red[t >> 6] = mx;
    __syncthreads();
    if (t == 0) {
        mx = fmaxf(fmaxf(red[0], red[1]), fmaxf(red[2], red[3]));
        unsigned u = __float_as_uint(mx);
        unsigned enc = (u & 0x80000000u) ? ~u : (u | 0x80000000u);
        atomicMax(&rowmaxenc[h], enc);
    }
}

// ---------------- kernel 5b: hard rows — exp/sum + partial PV ----------------
__global__ __launch_bounds__(256) void hardB_kernel(
    const float* __restrict__ Wh, const int* __restrict__ hardcnt,
    const float* __restrict__ ebuf, const unsigned* __restrict__ rowmaxenc,
    float* __restrict__ rowsum, float* __restrict__ acc) {
    const int h = blockIdx.x >> 5;
    const int chunk = blockIdx.x & 31;
    const int nh = min(*hardcnt, HMAX);
    if (h >= nh) return;
    const int t = threadIdx.x;
    unsigned enc = rowmaxenc[h];
    unsigned u = (enc & 0x80000000u) ? (enc & 0x7fffffffu) : ~enc;
    const float mx = __uint_as_float(u);
    const int j = (chunk << 8) + t;
    float p = expf(ebuf[h * N + j] - mx);
    __shared__ float pl[256];
    pl[t] = p;
    float ps = p;
#pragma unroll
    for (int off = 1; off < 64; off <<= 1) ps += __shfl_xor(ps, off, 64);
    if ((t & 63) == 0) atomicAdd(&rowsum[h], ps);
    __syncthreads();
    float o = 0.f;
    const float* base = &Wh[(ll)(chunk << 8) * FOUT + t];
#pragma unroll 4
    for (int jj = 0; jj < 256; ++jj) o = fmaf(pl[jj], base[(ll)jj * FOUT], o);
    atomicAdd(&acc[h * FOUT + t], o);
}

// ---------------- kernel 5c: hard rows — normalize+store (blocks<HMAX) + serial overflow tail ----------------
__global__ __launch_bounds__(256) void hardCtail_kernel(
    const float* __restrict__ Wh, const float* __restrict__ params,
    const int* __restrict__ adj, const float* __restrict__ x1, const float* __restrict__ x2,
    const float* __restrict__ w1, const float* __restrict__ w2,
    const int* __restrict__ hardcnt, const int* __restrict__ hardlist,
    const float* __restrict__ rowsum, const float* __restrict__ acc,
    float* __restrict__ out) {
    __shared__ float Whi[FOUT];
    __shared__ float ebuf[N];
    __shared__ float red[16];
    const int t = threadIdx.x;
    const int nh = *hardcnt;
    if (blockIdx.x < HMAX) {
        const int h = blockIdx.x;
        if (h >= min(nh, HMAX)) return;
        const int i = hardlist[h];
        float o = acc[h * FOUT + t] / rowsum[h];
        out[(ll)i * FOUT + t] = o > 0.f ? o : expm1f(o);
        return;
    }
    // overflow tail: h >= HMAX (normally no-op)
    for (int h = HMAX + (blockIdx.x - HMAX); h < nh; h += gridDim.x - HMAX) {
        const int i = hardlist[h];
        __syncthreads();
        Whi[t] = Wh[(ll)i * FOUT + t];
        __syncthreads();
        const float aC = params[0], cA = params[1], w1i = w1[i], w2i = w2[i];
        const float4* wi4 = (const float4*)Whi;
        for (int j0 = 0; j0 < N; j0 += 256) {
            int j = j0 + t;
            const float4* wr = (const float4*)&Wh[(ll)j * FOUT];
            float s = 0.f;
#pragma unroll 8
            for (int f = 0; f < 64; ++f) {
                float4 a = wi4[f], b = wr[f];
                s = fmaf(a.x, b.x, fmaf(a.y, b.y, fmaf(a.z, b.z, fmaf(a.w, b.w, s))));
            }
            float ev = fmaf(aC, s, cA);
            ev = fmaf(w1i, x1[j], ev);
            ev = fmaf(w2i, x2[j], ev);
            ebuf[j] = (adj[(ll)i * N + j] > 0) ? ev : NEGV;
        }
        __syncthreads();
        float mx = -INFINITY;
        for (int j = t; j < N; j += 256) mx = fmaxf(mx, ebuf[j]);
#pragma unroll
        for (int off = 1; off < 64; off <<= 1) mx = fmaxf(mx, __shfl_xor(mx, off, 64));
        if ((t & 63) == 0) red[t >> 6] = mx;
        __syncthreads();
        mx = fmaxf(fmaxf(red[0], red[1]), fmaxf(red[2], red[3]));
        float ls = 0.f;
        for (int j = t; j < N; j += 256) {
            float p = expf(ebuf[j] - mx);
            ebuf[j] = p;
            ls += p;
        }
#pragma unroll
        for (int off = 1; off < 64; off <<= 1) ls += __shfl_xor(ls, off, 64);
        if ((t & 63) == 0) red[8 + (t >> 6)] = ls;
        __syncthreads();
        ls = (red[8] + red[9]) + (red[10] + red[11]);
        float o0 = 0.f, o1 = 0.f, o2 = 0.f, o3 = 0.f;
        for (int j = 0; j < N; j += 4) {
            o0 = fmaf(ebuf[j + 0], Wh[(ll)(j + 0) * FOUT + t], o0);
            o1 = fmaf(ebuf[j + 1], Wh[(ll)(j + 1) * FOUT + t], o1);
            o2 = fmaf(ebuf[j + 2], Wh[(ll)(j + 2) * FOUT + t], o2);
            o3 = fmaf(ebuf[j + 3], Wh[(ll)(j + 3) * FOUT + t], o3);
        }
        float o = ((o0 + o1) + (o2 + o3)) / ls;
        out[(ll)i * FOUT + t] = o > 0.f ? o : expm1f(o);
    }
}

// ---------------- launch ----------------
extern "C" void kernel_launch(void* const* d_in, const int* in_sizes, int n_in,
                              void* d_out, int out_size, void* d_ws, size_t ws_size,
                              hipStream_t stream) {
    const float* h   = (const float*)d_in[0];
    const float* W   = (const float*)d_in[1];
    const float* Mui = (const float*)d_in[2];
    const int*   adj = (const int*)d_in[3];
    float* out = (float*)d_out;

    float* ws = (float*)d_ws;
    float* Wh     = ws;                         // 8192*256
    float* t1a    = Wh + N * FOUT;              // N
    float* x1     = t1a + N;
    float* x2     = x1 + N;
    float* w1     = x2 + N;
    float* w2     = w1 + N;
    float* nrm    = w2 + N;
    float* params = nrm + N;                    // 8
    float* ct1    = params + 8;                 // NCAND
    float* cx1    = ct1 + NCAND;
    float* cx2    = cx1 + NCAND;
    float* ubx    = cx2 + NCAND;                // 2
    float* o1v    = ubx + 2;                    // 1024
    float* celu   = o1v + 1024;                 // NCAND*FOUT = 4096
    float* ebuf   = celu + NCAND * FOUT;        // HMAX*N
    float* acc    = ebuf + HMAX * N;            // HMAX*FOUT
    float* rowsum = acc + HMAX * FOUT;          // HMAX
    int*   o1i       = (int*)(rowsum + HMAX);   // 1024
    int*   cidx      = o1i + 1024;              // NCAND
    int*   hardcnt   = cidx + NCAND;            // 1
    unsigned* gmaxb  = (unsigned*)(hardcnt + 1);// 1
    unsigned* rowmaxenc = gmaxb + 1;            // HMAX
    int*   hardlist  = (int*)(rowmaxenc + HMAX);// N

    wh_gemm<<<dim3(FOUT / 64, N / 64), 256, 0, stream>>>(h, W, Wh, gmaxb);
    factors2_kernel<<<N / 4, 256, 0, stream>>>(Wh, Mui, params, t1a, x1, x2, w1, w2, nrm);
    redtopk1_kernel<<<64, 64, 0, stream>>>(t1a, nrm, gmaxb, o1v, o1i);
    topk2_kernel<<<1, 1024, 0, stream>>>(o1v, o1i, t1a, x1, x2, Wh,
                                         cidx, ct1, cx1, cx2, ubx, hardcnt,
                                         acc, rowsum, rowmaxenc, celu);
    classify_kernel<<<N / 4, 256, 0, stream>>>(celu, params, adj, cidx, ct1, cx1, cx2, ubx,
                                               w1, w2, nrm, gmaxb, hardcnt, hardlist, out);
    hardA_kernel<<<32 * HMAX, 256, 0, stream>>>(Wh, params, adj, x1, x2, w1, w2,
                                                hardcnt, hardlist, ebuf, rowmaxenc);
    hardB_kernel<<<32 * HMAX, 256, 0, stream>>>(Wh, hardcnt, ebuf, rowmaxenc, rowsum, acc);
    hardCtail_kernel<<<HMAX + 128, 256, 0, stream>>>(Wh, params, adj, x1, x2, w1, w2,
                                                     hardcnt, hardlist, rowsum, acc, out);
    (void)n_in; (void)in_sizes; (void)out_size; (void)ws_size;
}